// Round 5
// baseline (1096.939 us; speedup 1.0000x reference)
//
#include <hip/hip_runtime.h>
#include <hip/hip_bf16.h>
#include <math.h>

#define Bq 2
#define Sq 1024
#define Dq 1024
#define Hq 16
#define DHq 64
#define FFq 4096
#define Eq 4
#define Kq 64
#define Mq 256
#define GATEq 128
#define BSq (Bq*Sq)
#define DEPTHF 1.25f
#define SCALEF 0.125f
#define DD (Dq*Dq)
#define PLANE ((size_t)BSq*Dq)

typedef __hip_bfloat16 bf16;
typedef __attribute__((ext_vector_type(8))) __bf16 bf16x8;
typedef __attribute__((ext_vector_type(4))) float f32x4;

__device__ __forceinline__ float toF(float v){ return v; }
__device__ __forceinline__ float toF(bf16 v){ return __bfloat162float(v); }
__device__ __forceinline__ void stF(float* p, size_t i, float v){ p[i] = v; }
__device__ __forceinline__ void stF(bf16* p, size_t i, float v){ p[i] = __float2bfloat16(v); }
__device__ __forceinline__ float gelu_f(float x){
  const float c = 0.7978845608028654f;
  return 0.5f*x*(1.0f + tanhf(c*(x + 0.044715f*x*x*x)));
}
__device__ __forceinline__ unsigned short bfb(float f){
  bf16 h = __float2bfloat16(f);
  return *(unsigned short*)&h;
}
// inverse of the monotone uint map (uu = s<0 ? ~bits : bits|0x80000000)
__device__ __forceinline__ float thr_decode(unsigned c){
  unsigned ub = (c & 0x80000000u) ? (c & 0x7FFFFFFFu) : ~c;
  return __uint_as_float(ub);
}
// async global->LDS, 16B per lane; lds pointer must be wave-uniform (chunk base)
__device__ __forceinline__ void async_lds16(const void* g, void* lds) {
  __builtin_amdgcn_global_load_lds(
      (const __attribute__((address_space(1))) void*)(unsigned long long)(uintptr_t)g,
      (__attribute__((address_space(3))) void*)(unsigned)(uintptr_t)lds, 16, 0, 0);
}

// ---------------- dtype detector ----------------
__global__ __launch_bounds__(256)
void detect_kernel(const unsigned* __restrict__ xw, int* __restrict__ flag)
{
  __shared__ int cnt;
  if (threadIdx.x == 0) cnt = 0;
  __syncthreads();
  int c = 0;
  for (int i = threadIdx.x; i < 4096; i += 256) {
    unsigned e = (xw[i] >> 7) & 0xFFu;
    c += (e >= 0x70u && e <= 0x8Fu) ? 1 : 0;
  }
#pragma unroll
  for (int o = 32; o >= 1; o >>= 1) c += __shfl_xor(c, o);
  if ((threadIdx.x & 63) == 0) atomicAdd(&cnt, c);
  __syncthreads();
  if (threadIdx.x == 0) *flag = (cnt > 2048) ? 1 : 0;
}

// ---------------- convert x -> bf16 ----------------
__global__ __launch_bounds__(256)
void conv_x_kernel(const int* __restrict__ flag, const void* __restrict__ x, bf16* __restrict__ xb)
{
  int f = *flag;
  int i0 = (blockIdx.x*256 + threadIdx.x)*4;
  if (i0 >= BSq*Dq) return;
  if (f) {
    const bf16* s = (const bf16*)x;
#pragma unroll
    for (int k=0;k<4;k++) xb[i0+k] = s[i0+k];
  } else {
    const float* s = (const float*)x;
#pragma unroll
    for (int k=0;k<4;k++) xb[i0+k] = __float2bfloat16(s[i0+k]);
  }
}

// ---------------- pack all biases into bf16 arena ----------------
template<typename IT>
__device__ void packseg(bf16* dst, const IT* src, int len)
{
  for (int i = threadIdx.x; i < len; i += 256) dst[i] = __float2bfloat16(toF(src[i]));
}
__global__ __launch_bounds__(256)
void pack_bias_kernel(const int* __restrict__ flag, bf16* arena,
    const void* bq, const void* bk, const void* bv, const void* bo,
    const void* sq, const void* sk, const void* sv, const void* so,
    const void* pq, const void* pk, const void* pv, const void* po,
    const void* f1, const void* f2)
{
  int f = *flag;
  if (f) {
    packseg(arena+0,     (const bf16*)bq, 4096); packseg(arena+4096,  (const bf16*)bk, 4096);
    packseg(arena+8192,  (const bf16*)bv, 4096); packseg(arena+12288, (const bf16*)bo, 4096);
    packseg(arena+16384, (const bf16*)sq, 1024); packseg(arena+17408, (const bf16*)sk, 1024);
    packseg(arena+18432, (const bf16*)sv, 1024); packseg(arena+19456, (const bf16*)so, 1024);
    packseg(arena+20480, (const bf16*)pq, 1024); packseg(arena+21504, (const bf16*)pk, 1024);
    packseg(arena+22528, (const bf16*)pv, 1024); packseg(arena+23552, (const bf16*)po, 1024);
    packseg(arena+24576, (const bf16*)f1, 4096); packseg(arena+28672, (const bf16*)f2, 1024);
  } else {
    packseg(arena+0,     (const float*)bq, 4096); packseg(arena+4096,  (const float*)bk, 4096);
    packseg(arena+8192,  (const float*)bv, 4096); packseg(arena+12288, (const float*)bo, 4096);
    packseg(arena+16384, (const float*)sq, 1024); packseg(arena+17408, (const float*)sk, 1024);
    packseg(arena+18432, (const float*)sv, 1024); packseg(arena+19456, (const float*)so, 1024);
    packseg(arena+20480, (const float*)pq, 1024); packseg(arena+21504, (const float*)pk, 1024);
    packseg(arena+22528, (const float*)pv, 1024); packseg(arena+23552, (const float*)po, 1024);
    packseg(arena+24576, (const float*)f1, 4096); packseg(arena+28672, (const float*)f2, 1024);
  }
}

// ---------------- pack wf (DH x M) -> wfT (M x DH) bf16 ----------------
template<typename IT>
__device__ void packwft_body(const IT* __restrict__ wf, bf16* __restrict__ wft)
{
  int i = blockIdx.x*256 + threadIdx.x;
  if (i >= DHq*Mq) return;
  int d = i >> 8, m = i & 255;
  wft[m*DHq + d] = __float2bfloat16(toF(wf[(size_t)d*Mq + m]));
}
__global__ __launch_bounds__(256)
void pack_wft_kernel(const int* __restrict__ flag, const void* wf, bf16* wft)
{
  if (*flag) packwft_body<bf16>((const bf16*)wf, wft);
  else       packwft_body<float>((const float*)wf, wft);
}

// ---------------- pipelined MFMA GEMM core (2-phase, double-buffered LDS) ----------------
template<typename WT>
__device__ void gemm_core(bf16* As, unsigned* Bs,
    const bf16* __restrict__ A, int lda, const WT* __restrict__ W,
    const bf16* __restrict__ barena, int biasOff,
    const float* __restrict__ rowscale, bf16* __restrict__ C,
    float* __restrict__ Cf, int N, int K, int act)
{
  int tid = threadIdx.x;
  int lane = tid & 63, wave = tid >> 6;
  int wr = wave >> 1, wc = wave & 1;
  int bm = blockIdx.x * 128, bn = blockIdx.y * 128;

  int arow1 = wave*16 + (lane>>2);
  int akey = (arow1 >> 1) & 3;
  int acol = ((lane & 3) ^ akey) * 8;
  const bf16* aP1 = A + (size_t)(bm + arow1)*lda + acol;
  const bf16* aP2 = A + (size_t)(bm + arow1 + 64)*lda + acol;

  int kp = tid >> 4, nb8 = (tid & 15)*8;
  const WT* wP = W + (size_t)(2*kp)*N + bn + nb8;

  f32x4 acc[4][4];
#pragma unroll
  for (int i=0;i<4;i++)
#pragma unroll
    for (int j=0;j<4;j++) acc[i][j] = (f32x4){0.f,0.f,0.f,0.f};

  int m = lane & 15, q = lane >> 4;
  int akey2 = (m >> 1) & 3;
  int aq = (q ^ akey2) * 8;

  const int T = K >> 5;
  uint4 rwa, rwb, rwc, rwd;

  async_lds16(aP1, As + wave*512);
  async_lds16(aP2, As + (wave+4)*512);
  aP1 += 32; aP2 += 32;
  if constexpr (sizeof(WT) == 2) {
    rwa = *(const uint4*)wP;
    rwb = *(const uint4*)(wP + N);
  } else {
    const float* f0 = (const float*)wP;
    const float* f1 = (const float*)(wP + N);
    rwa = *(const uint4*)f0; rwb = *(const uint4*)(f0+4);
    rwc = *(const uint4*)f1; rwd = *(const uint4*)(f1+4);
  }
  wP += (size_t)32*N;

  for (int t = 0; t < T; t++) {
    int cur = t & 1;
    unsigned p[8];
    if constexpr (sizeof(WT) == 2) {
      p[0] = (rwa.x & 0xFFFFu) | (rwb.x << 16);  p[1] = (rwa.x >> 16) | (rwb.x & 0xFFFF0000u);
      p[2] = (rwa.y & 0xFFFFu) | (rwb.y << 16);  p[3] = (rwa.y >> 16) | (rwb.y & 0xFFFF0000u);
      p[4] = (rwa.z & 0xFFFFu) | (rwb.z << 16);  p[5] = (rwa.z >> 16) | (rwb.z & 0xFFFF0000u);
      p[6] = (rwa.w & 0xFFFFu) | (rwb.w << 16);  p[7] = (rwa.w >> 16) | (rwb.w & 0xFFFF0000u);
    } else {
      p[0] = (unsigned)bfb(__uint_as_float(rwa.x)) | ((unsigned)bfb(__uint_as_float(rwc.x)) << 16);
      p[1] = (unsigned)bfb(__uint_as_float(rwa.y)) | ((unsigned)bfb(__uint_as_float(rwc.y)) << 16);
      p[2] = (unsigned)bfb(__uint_as_float(rwa.z)) | ((unsigned)bfb(__uint_as_float(rwc.z)) << 16);
      p[3] = (unsigned)bfb(__uint_as_float(rwa.w)) | ((unsigned)bfb(__uint_as_float(rwc.w)) << 16);
      p[4] = (unsigned)bfb(__uint_as_float(rwb.x)) | ((unsigned)bfb(__uint_as_float(rwd.x)) << 16);
      p[5] = (unsigned)bfb(__uint_as_float(rwb.y)) | ((unsigned)bfb(__uint_as_float(rwd.y)) << 16);
      p[6] = (unsigned)bfb(__uint_as_float(rwb.z)) | ((unsigned)bfb(__uint_as_float(rwd.z)) << 16);
      p[7] = (unsigned)bfb(__uint_as_float(rwb.w)) | ((unsigned)bfb(__uint_as_float(rwd.w)) << 16);
    }
    unsigned* bD = Bs + cur*2112 + kp*132 + nb8;
    *(uint4*)(bD)     = make_uint4(p[0],p[1],p[2],p[3]);
    *(uint4*)(bD + 4) = make_uint4(p[4],p[5],p[6],p[7]);
    asm volatile("s_waitcnt vmcnt(0)" ::: "memory");
    __syncthreads();
    if (t + 1 < T) {
      bf16* asn = As + ((t+1)&1)*4096;
      async_lds16(aP1, asn + wave*512);
      async_lds16(aP2, asn + (wave+4)*512);
      aP1 += 32; aP2 += 32;
      if constexpr (sizeof(WT) == 2) {
        rwa = *(const uint4*)wP;
        rwb = *(const uint4*)(wP + N);
      } else {
        const float* f0 = (const float*)wP;
        const float* f1 = (const float*)(wP + N);
        rwa = *(const uint4*)f0; rwb = *(const uint4*)(f0+4);
        rwc = *(const uint4*)f1; rwd = *(const uint4*)(f1+4);
      }
      wP += (size_t)32*N;
    }
    const bf16* asc = As + cur*4096;
    const unsigned* bsc = Bs + cur*2112;
    bf16x8 av[4], bv[4];
#pragma unroll
    for (int i=0;i<4;i++)
      av[i] = *(const bf16x8*)&asc[(wr*64 + i*16 + m)*32 + aq];
#pragma unroll
    for (int j=0;j<4;j++) {
      int n = wc*64 + j*16 + m;
      unsigned b0 = bsc[(q*4+0)*132 + n];
      unsigned b1 = bsc[(q*4+1)*132 + n];
      unsigned b2 = bsc[(q*4+2)*132 + n];
      unsigned b3 = bsc[(q*4+3)*132 + n];
      uint4 bb = make_uint4(b0,b1,b2,b3);
      bv[j] = *(const bf16x8*)&bb;
    }
#pragma unroll
    for (int i=0;i<4;i++)
#pragma unroll
      for (int j=0;j<4;j++)
        acc[i][j] = __builtin_amdgcn_mfma_f32_16x16x32_bf16(av[i], bv[j], acc[i][j], 0, 0, 0);
  }

#pragma unroll
  for (int i=0;i<4;i++) {
    int row0 = bm + wr*64 + i*16 + q*4;
#pragma unroll
    for (int j=0;j<4;j++) {
      int col = bn + wc*64 + j*16 + m;
      float bvv = barena ? toF(barena[biasOff + col]) : 0.f;
#pragma unroll
      for (int r=0;r<4;r++) {
        size_t idx = (size_t)(row0 + r)*N + col;
        if (Cf) {
          Cf[idx] = acc[i][j][r];
        } else {
          float v = acc[i][j][r] + bvv;
          if (act) v = gelu_f(v);
          if (rowscale) v *= rowscale[row0 + r];
          C[idx] = __float2bfloat16(v);
        }
      }
    }
  }
}

// six-way z-batched GEMM (QKV pairs / all O-projections)
__global__ __launch_bounds__(256, 3)
void gemm6_k(const int* __restrict__ flag, const bf16* Abase, long az,
    const void* w0, const void* w1, const void* w2,
    const void* w3, const void* w4, const void* w5,
    long e0, long e1, long e2, long e3, long e4, long e5,
    int b0, int b1, int b2, int b3, int b4, int b5,
    const float* r0, const float* r1, const float* r2,
    const float* r3, const float* r4, const float* r5,
    bf16* c0, bf16* c1, bf16* c2, bf16* c3, bf16* c4, bf16* c5,
    const bf16* barena, int N, int K)
{
  __shared__ bf16 As[2*4096];
  __shared__ unsigned Bs[2*2112];
  int z = blockIdx.z;
  const void* Wp = (z==0)?w0:(z==1)?w1:(z==2)?w2:(z==3)?w3:(z==4)?w4:w5;
  long eo        = (z==0)?e0:(z==1)?e1:(z==2)?e2:(z==3)?e3:(z==4)?e4:e5;
  int bo         = (z==0)?b0:(z==1)?b1:(z==2)?b2:(z==3)?b3:(z==4)?b4:b5;
  const float* rs= (z==0)?r0:(z==1)?r1:(z==2)?r2:(z==3)?r3:(z==4)?r4:r5;
  bf16* C        = (z==0)?c0:(z==1)?c1:(z==2)?c2:(z==3)?c3:(z==4)?c4:c5;
  const bf16* A  = Abase + (size_t)z*az;
  if (*flag) gemm_core<bf16>(As, Bs, A, K, (const bf16*)Wp + eo, barena, bo, rs, C, nullptr, N, K, 0);
  else       gemm_core<float>(As, Bs, A, K, (const float*)Wp + eo, barena, bo, rs, C, nullptr, N, K, 0);
}

// single-matrix GEMM with optional split-K (z = K-chunk, f32 partial out)
__global__ __launch_bounds__(256, 3)
void gemm1_k(const int* __restrict__ flag, const bf16* A, int lda, const void* W,
             const bf16* barena, int biasOff, const float* rowscale,
             bf16* C, float* Cf, long cfz, int N, int K, int act, int kz)
{
  __shared__ bf16 As[2*4096];
  __shared__ unsigned Bs[2*2112];
  int z = blockIdx.z;
  const bf16* Az = A + (size_t)z*kz;
  long wo = (size_t)z*kz*N;
  float* Cfz = Cf ? (Cf + (size_t)z*cfz) : nullptr;
  if (*flag) gemm_core<bf16>(As, Bs, Az, lda, (const bf16*)W + wo, barena, biasOff, rowscale, C, Cfz, N, K, act);
  else       gemm_core<float>(As, Bs, Az, lda, (const float*)W + wo, barena, biasOff, rowscale, C, Cfz, N, K, act);
}

// ---------------- FFN2 split-K combine: out = (sum partials + bias) * rowscale ----------------
__global__ __launch_bounds__(256)
void combine_ffn2(const float* __restrict__ pf, const bf16* __restrict__ barena,
                  const float* __restrict__ rs, bf16* __restrict__ out)
{
  int i0 = (blockIdx.x*256 + threadIdx.x)*4;
  float4 s0 = *(const float4*)(pf + i0);
  float4 s1 = *(const float4*)(pf + PLANE + i0);
  float4 s2 = *(const float4*)(pf + 2*PLANE + i0);
  float4 s3 = *(const float4*)(pf + 3*PLANE + i0);
  int row = i0 >> 10, col = i0 & 1023;
  float r = rs[row];
  out[i0+0] = __float2bfloat16((s0.x+s1.x+s2.x+s3.x + toF(barena[28672+col+0])) * r);
  out[i0+1] = __float2bfloat16((s0.y+s1.y+s2.y+s3.y + toF(barena[28672+col+1])) * r);
  out[i0+2] = __float2bfloat16((s0.z+s1.z+s2.z+s3.z + toF(barena[28672+col+2])) * r);
  out[i0+3] = __float2bfloat16((s0.w+s1.w+s2.w+s3.w + toF(barena[28672+col+3])) * r);
}

// ---------------- V transpose: V(b,s,h,d) -> Vt(b,h,d,s), z-batched ----------------
__global__ __launch_bounds__(256)
void vtrans_kernel(const bf16* __restrict__ Vb, long vz, bf16* __restrict__ Vtb, long vtz)
{
  __shared__ bf16 t[64][72];
  const bf16* V = Vb + (size_t)blockIdx.z*vz;
  bf16* Vt = Vtb + (size_t)blockIdx.z*vtz;
  int bh = blockIdx.x;
  int sc_ = blockIdx.y;
  int b = bh >> 4, h = bh & 15;
  int tid = threadIdx.x;
  {
    int s = tid >> 2, dd = (tid & 3) * 16;
    const bf16* src = &V[((size_t)b*Sq + sc_*64 + s)*Dq + h*64 + dd];
    uint4 a0 = *(const uint4*)src;
    uint4 a1 = *(const uint4*)(src + 8);
    *(uint4*)&t[s][dd]     = a0;
    *(uint4*)&t[s][dd + 8] = a1;
  }
  __syncthreads();
  {
    int d = tid >> 2, sp = (tid & 3) * 16;
    unsigned short buf[16];
#pragma unroll
    for (int e = 0; e < 16; e++) {
      bf16 v = t[sp + e][d];
      buf[e] = *(unsigned short*)&v;
    }
    bf16* dst = &Vt[((size_t)bh*DHq + d)*Sq + sc_*64 + sp];
    *(uint4*)dst       = *(uint4*)&buf[0];
    *(uint4*)(dst + 8) = *(uint4*)&buf[8];
  }
}

// ---------------- MFMA fused attention (dense / exact top-K sparse) ----------------
// R5: XCD-aware block swizzle — all 64 row-blocks of one (b,h) land on ONE XCD
// (position p runs on XCD p%8). K/Vt for that (b,h) stay L2-resident (~256 KB;
// 4 (b,h) groups per XCD ~1 MB << 4 MB L2) instead of thrashing to L3/HBM.
template<int SPARSE>
__global__ __launch_bounds__(256, 4)
void attn_kernel(const bf16* __restrict__ Q, const bf16* __restrict__ K,
                 const bf16* __restrict__ Vt, bf16* __restrict__ O)
{
  const int PAST = 1032;
  __shared__ bf16 pa[16*PAST];
  __shared__ float partA[64], partB[64];
  __shared__ int cntb[2][64];

  int p_ = blockIdx.x;
  int g_ = (p_ & 7)*4 + ((p_ >> 3) & 3);   // (b,h) group: constant XCD per group
  int rb = p_ >> 5;                        // 0..63 row-block within the group
  int h  = g_ & 15;
  int b  = g_ >> 4;
  int tid = threadIdx.x, lane = tid & 63, wave = tid >> 6;
  int m = lane & 15, q = lane >> 4;
  size_t base = ((size_t)b*Sq)*Dq + (size_t)h*DHq;
  int q0 = rb*16;

  const bf16* qrow = &Q[base + (size_t)(q0+m)*Dq + q*8];
  bf16x8 aq0 = *(const bf16x8*)qrow;
  bf16x8 aq1 = *(const bf16x8*)(qrow + 32);

  f32x4 cc[16];
#pragma unroll
  for (int t = 0; t < 16; t++) {
    int j0 = wave*256 + t*16;
    const bf16* kp = &K[base + (size_t)(j0+m)*Dq + q*8];
    bf16x8 b0 = *(const bf16x8*)kp;
    bf16x8 b1 = *(const bf16x8*)(kp + 32);
    f32x4 c = {0.f,0.f,0.f,0.f};
    c = __builtin_amdgcn_mfma_f32_16x16x32_bf16(aq0, b0, c, 0, 0, 0);
    c = __builtin_amdgcn_mfma_f32_16x16x32_bf16(aq1, b1, c, 0, 0, 0);
#pragma unroll
    for (int r=0;r<4;r++) c[r] *= SCALEF;
    cc[t] = c;
  }

  unsigned lo[4] = {0u,0u,0u,0u};
  if (SPARSE) {
    int cnt_cur[4] = {Sq, Sq, Sq, Sq};
    for (int bit = 31; bit >= 0; bit--) {
      int par = bit & 1;
      unsigned cand[4];
      float candf[4];
      int c4[4] = {0,0,0,0};
#pragma unroll
      for (int r=0;r<4;r++) {
        cand[r] = lo[r] | (1u << bit);
        candf[r] = thr_decode(cand[r]);
      }
#pragma unroll
      for (int t=0;t<16;t++)
#pragma unroll
        for (int r=0;r<4;r++) c4[r] += (cc[t][r] >= candf[r]) ? 1 : 0;
#pragma unroll
      for (int o=1;o<16;o<<=1)
#pragma unroll
        for (int r=0;r<4;r++) c4[r] += __shfl_xor(c4[r], o);
      if (m == 0) {
#pragma unroll
        for (int r=0;r<4;r++) cntb[par][wave*16 + q*4 + r] = c4[r];
      }
      __syncthreads();
      int done = 1;
#pragma unroll
      for (int r=0;r<4;r++) {
        int row = q*4 + r;
        int tot = cntb[par][row] + cntb[par][16+row] + cntb[par][32+row] + cntb[par][48+row];
        if (tot >= Kq) { lo[r] = cand[r]; cnt_cur[r] = tot; }
        done &= (cnt_cur[r] == Kq) ? 1 : 0;
      }
      done &= __shfl_xor(done, 16);
      done &= __shfl_xor(done, 32);
      if (done) break;
    }
  }

  float mrow[4];
#pragma unroll
  for (int r=0;r<4;r++) {
    float v = -1e30f;
#pragma unroll
    for (int t=0;t<16;t++) v = fmaxf(v, cc[t][r]);
#pragma unroll
    for (int o=1;o<16;o<<=1) v = fmaxf(v, __shfl_xor(v, o));
    mrow[r] = v;
  }
  if (m == 0) {
#pragma unroll
    for (int r=0;r<4;r++) partA[wave*16 + q*4 + r] = mrow[r];
  }
  __syncthreads();
#pragma unroll
  for (int r=0;r<4;r++) {
    int row = q*4 + r;
    mrow[r] = fmaxf(fmaxf(partA[row], partA[16+row]), fmaxf(partA[32+row], partA[48+row]));
  }

  float thrf[4];
  if (SPARSE) {
#pragma unroll
    for (int r=0;r<4;r++) {
      thrf[r] = (!(lo[r] & 0x80000000u) && lo[r] <= 0x007FFFFFu)
                    ? -INFINITY : thr_decode(lo[r]);
    }
  }
  float rsum[4] = {0.f,0.f,0.f,0.f};
#pragma unroll
  for (int t=0;t<16;t++) {
    int col = wave*256 + t*16 + m;
#pragma unroll
    for (int r=0;r<4;r++) {
      float p;
      if (SPARSE) p = (cc[t][r] >= thrf[r]) ? __expf(cc[t][r] - mrow[r]) : 0.f;
      else        p = __expf(cc[t][r] - mrow[r]);
      rsum[r] += p;
      pa[(q*4+r)*PAST + col] = __float2bfloat16(p);
    }
  }
#pragma unroll
  for (int r=0;r<4;r++)
#pragma unroll
    for (int o=1;o<16;o<<=1) rsum[r] += __shfl_xor(rsum[r], o);
  if (m == 0) {
#pragma unroll
    for (int r=0;r<4;r++) partB[wave*16 + q*4 + r] = rsum[r];
  }
  __syncthreads();
#pragma unroll
  for (int r=0;r<4;r++) {
    int row = q*4 + r;
    rsum[r] = partB[row] + partB[16+row] + partB[32+row] + partB[48+row];
    rsum[r] = fmaxf(rsum[r], 1e-30f);
  }

  const bf16* vtp = &Vt[((size_t)(b*Hq + h)*DHq + wave*16 + m)*Sq];
  f32x4 oc = {0.f,0.f,0.f,0.f};
#pragma unroll 8
  for (int ks = 0; ks < 32; ks++) {
    bf16x8 af = *(const bf16x8*)&pa[m*PAST + ks*32 + q*8];
    bf16x8 bv = *(const bf16x8*)&vtp[ks*32 + q*8];
    oc = __builtin_amdgcn_mfma_f32_16x16x32_bf16(af, bv, oc, 0, 0, 0);
  }
#pragma unroll
  for (int r=0;r<4;r++) {
    O[base + (size_t)(q0 + q*4 + r)*Dq + wave*16 + m] = __float2bfloat16(oc[r] / rsum[r]);
  }
}

// ---------------- performer pass 1 (MFMA) ----------------
__global__ __launch_bounds__(256)
void perf_kv_mfma(const bf16* __restrict__ Kb, const bf16* __restrict__ Vt,
                  const bf16* __restrict__ wft, bf16* __restrict__ kvb,
                  float* __restrict__ zg)
{
  __shared__ bf16 pbuf[4][32*40];
  __shared__ float kvred[4][64*32];
  __shared__ float zred[4][32];

  int bh = blockIdx.x;
  int mg = blockIdx.y;
  int b = bh >> 4, h = bh & 15;
  int tid = threadIdx.x, lane = tid & 63, wave = tid >> 6;
  int ml = lane & 15, q = lane >> 4;
  size_t kbase = ((size_t)b*Sq)*Dq + (size_t)h*DHq;
  const bf16* vtb = Vt + (size_t)bh*DHq*Sq;
  int sw0 = wave*256;
  bf16* pw = pbuf[wave];

  bf16x8 awf[2][2];
#pragma unroll
  for (int t=0;t<2;t++) {
    const bf16* p = &wft[(size_t)(mg*32 + t*16 + ml)*DHq + q*8];
    awf[t][0] = *(const bf16x8*)p;
    awf[t][1] = *(const bf16x8*)(p + 32);
  }

  f32x4 acc[4][2];
#pragma unroll
  for (int dt=0;dt<4;dt++)
#pragma unroll
    for (int t=0;t<2;t++) acc[dt][t] = (f32x4){0.f,0.f,0.f,0.f};
  float zacc[2][4] = {{0.f,0.f,0.f,0.f},{0.f,0.f,0.f,0.f}};

  for (int st = 0; st < 8; st++) {
    int s0 = sw0 + st*32;
    f32x4 pk[2][2];
#pragma unroll
    for (int sc=0;sc<2;sc++) {
      const bf16* kp = &Kb[kbase + (size_t)(s0 + sc*16 + ml)*Dq + q*8];
      bf16x8 b0 = *(const bf16x8*)kp;
      bf16x8 b1 = *(const bf16x8*)(kp + 32);
#pragma unroll
      for (int t=0;t<2;t++) {
        f32x4 c = (f32x4){0.f,0.f,0.f,0.f};
        c = __builtin_amdgcn_mfma_f32_16x16x32_bf16(awf[t][0], b0, c, 0, 0, 0);
        c = __builtin_amdgcn_mfma_f32_16x16x32_bf16(awf[t][1], b1, c, 0, 0, 0);
        pk[t][sc] = c;
      }
    }
#pragma unroll
    for (int t=0;t<2;t++)
#pragma unroll
      for (int sc=0;sc<2;sc++)
#pragma unroll
        for (int r=0;r<4;r++) {
          float v = fmaxf(pk[t][sc][r], 0.f);
          zacc[t][r] += v;
          pw[(t*16 + q*4 + r)*40 + sc*16 + ml] = __float2bfloat16(v);
        }
#pragma unroll
    for (int dt=0;dt<4;dt++) {
      bf16x8 av = *(const bf16x8*)&vtb[(size_t)(dt*16 + ml)*Sq + s0 + q*8];
#pragma unroll
      for (int t=0;t<2;t++) {
        bf16x8 bp = *(const bf16x8*)&pw[(t*16 + ml)*40 + q*8];
        acc[dt][t] = __builtin_amdgcn_mfma_f32_16x16x32_bf16(av, bp, acc[dt][t], 0, 0, 0);
      }
    }
  }

#pragma unroll
  for (int dt=0;dt<4;dt++)
#pragma unroll
    for (int t=0;t<2;t++)
#pragma unroll
      for (int r=0;r<4;r++)
        kvred[wave][(dt*16 + q*4 + r)*32 + t*16 + ml] = acc[dt][t][r];
#pragma unroll
  for (int t=0;t<2;t++)
#pragma unroll
    for (int r=0;r<4;r++) {
      float v = zacc[t][r];
#pragma unroll
      for (int o=1;o<16;o<<=1) v += __shfl_xor(v, o);
      if (ml == 0) zred[wave][t*16 + q*4 + r] = v;
    }
  __syncthreads();
  for (int p = tid; p < 2048; p += 256) {
    float s = kvred[0][p] + kvred[1][p] + kvred[2][p] + kvred[3][p];
    int d = p >> 5, mloc = p & 31;
    kvb[(size_t)bh*(DHq*Mq) + d*Mq + mg*32 + mloc] = __float2bfloat16(s);
  }
  if (tid < 32) {
    float s = zred[0][tid] + zred[1][tid] + zred[2][tid] + zred[3][tid];
    zg[bh*Mq + mg*32 + tid] = s;
  }
}

// ---------------- performer pass 2 (MFMA) ----------------
__global__ __launch_bounds__(256)
void perf_out_mfma(const bf16* __restrict__ Q, const bf16* __restrict__ wft,
                   const bf16* __restrict__ kvb, const float* __restrict__ zg,
                   bf16* __restrict__ O)
{
  const int PQST = 264;
  __shared__ bf16 pa2[64*PQST];
  __shared__ float zs[Mq];

  int blk = blockIdx.x;
  int sc_ = blk & 15;
  int bh  = blk >> 4;
  int b = bh >> 4, h = bh & 15;
  int tid = threadIdx.x, lane = tid & 63, wave = tid >> 6;
  int ml = lane & 15, q = lane >> 4;
  size_t base = ((size_t)b*Sq)*Dq + (size_t)h*DHq;
  int s0 = sc_*64;

  zs[tid] = zg[bh*Mq + tid];

  const bf16* qp = &Q[base + (size_t)(s0 + wave*16 + ml)*Dq + q*8];
  bf16x8 aq0 = *(const bf16x8*)qp;
  bf16x8 aq1 = *(const bf16x8*)(qp + 32);
  __syncthreads();

  f32x4 pq[16];
#pragma unroll
  for (int mt=0;mt<16;mt++) {
    const bf16* wp = &wft[(size_t)(mt*16 + ml)*DHq + q*8];
    bf16x8 b0 = *(const bf16x8*)wp;
    bf16x8 b1 = *(const bf16x8*)(wp + 32);
    f32x4 c = (f32x4){0.f,0.f,0.f,0.f};
    c = __builtin_amdgcn_mfma_f32_16x16x32_bf16(aq0, b0, c, 0, 0, 0);
    c = __builtin_amdgcn_mfma_f32_16x16x32_bf16(aq1, b1, c, 0, 0, 0);
    pq[mt] = c;
  }

  float den[4] = {1e-6f, 1e-6f, 1e-6f, 1e-6f};
#pragma unroll
  for (int mt=0;mt<16;mt++)
#pragma unroll
    for (int r=0;r<4;r++) {
      float v = fmaxf(pq[mt][r], 0.f);
      den[r] += v * zs[mt*16 + ml];
      pa2[(wave*16 + q*4 + r)*PQST + mt*16 + ml] = __float2bfloat16(v);
    }
#pragma unroll
  for (int r=0;r<4;r++)
#pragma unroll
    for (int o=1;o<16;o<<=1) den[r] += __shfl_xor(den[r], o);
  __syncthreads();

  const bf16* kvp = kvb + (size_t)bh*(DHq*Mq);
  f32x4 oc[4];
#pragma unroll
  for (int dt=0;dt<4;dt++) oc[dt] = (f32x4){0.f,0.f,0.f,0.f};
#pragma unroll
  for (int ks=0; ks<8; ks++) {
    bf16x8 ap = *(const bf16x8*)&pa2[(wave*16 + ml)*PQST + ks*32 + q*8];
#pragma unroll
    for (int dt=0;dt<4;dt++) {
      bf16x8 bk = *(const bf16x8*)&kvp[(size_t)(dt*16 + ml)*Mq + ks*32 + q*8];
      oc[dt] = __builtin_amdgcn_mfma_f32_16x16x32_bf16(ap, bk, oc[dt], 0, 0, 0);
    }
  }
#pragma unroll
  for (int dt=0;dt<4;dt++)
#pragma unroll
    for (int r=0;r<4;r++)
      O[base + (size_t)(s0 + wave*16 + q*4 + r)*Dq + dt*16 + ml] =
          __float2bfloat16(oc[dt][r] / den[r]);
}

// ---------------- LayerNorm ----------------
template<typename IT>
__device__ void ln_body(float* buf, float* red, const IT* __restrict__ xb,
                        const void* Ap, const void* Bp,
                        const IT* __restrict__ g, const IT* __restrict__ be,
                        void* out, int mode)
{
  int row = blockIdx.x;
  int tid = threadIdx.x;
  size_t off = (size_t)row*Dq;
  for (int dd = tid; dd < Dq; dd += 256) {
    float v;
    if (mode == 0)      v = toF(xb[off+dd]) + toF(((const bf16*)Ap)[off+dd]);
    else if (mode == 1) v = toF(((const bf16*)Ap)[off+dd]) + toF(((const bf16*)Bp)[off+dd]);
    else if (mode == 3) {
      const bf16* P = (const bf16*)Ap;
      v = toF(xb[off+dd]);
#pragma unroll
      for (int p=0;p<6;p++) v += toF(P[(size_t)p*PLANE + off + dd]);
    }
    else                v = toF(((const bf16*)Ap)[off+dd]);
    buf[dd] = v;
  }
  __syncthreads();
  float s = 0.f, q = 0.f;
  for (int dd = tid; dd < Dq; dd += 256) { float v = buf[dd]; s += v; q += v*v; }
#pragma unroll
  for (int o=32;o>=1;o>>=1) { s += __shfl_xor(s,o); q += __shfl_xor(q,o); }
  int w = tid >> 6;
  if ((tid & 63) == 0) { red[w] = s; red[4+w] = q; }
  __syncthreads();
  if (tid == 0) {
    float S1 = red[0]+red[1]+red[2]+red[3];
    float Q1 = red[4]+red[5]+red[6]+red[7];
    float mu = S1 / (float)Dq;
    float var = Q1 / (float)Dq - mu*mu;
    red[8] = mu; red[9] = rsqrtf(fmaxf(var, 0.f) + 1e-5f);
  }
  __syncthreads();
  float mu = red[8], inv = red[9];
  for (int dd = tid; dd < Dq; dd += 256) {
    float v = (buf[dd]-mu)*inv*toF(g[dd]) + toF(be[dd]);
    if (mode == 2) stF((IT*)out, off+dd, v);
    else           stF((bf16*)out, off+dd, v);
  }
}

__global__ __launch_bounds__(256)
void ln_kernel(const int* __restrict__ flag, const void* xb, const void* A, const void* Bv,
               const void* g, const void* be, void* out, int mode)
{
  __shared__ float buf[Dq];
  __shared__ float red[10];
  if (*flag) ln_body<bf16>(buf, red, (const bf16*)xb, A, Bv, (const bf16*)g, (const bf16*)be, out, mode);
  else       ln_body<float>(buf, red, (const float*)xb, A, Bv, (const float*)g, (const float*)be, out, mode);
}

// ---------------- avg over S (coalesced rows, atomic column partials; writes RAW SUMS) ----------------
__global__ __launch_bounds__(256)
void avg2_kernel(const int* __restrict__ flag, const void* __restrict__ x, float* __restrict__ avgsum)
{
  int b  = blockIdx.x >> 4;
  int sc = blockIdx.x & 15;
  int t = threadIdx.x;
  int c0 = t*4;
  float a0=0.f,a1=0.f,a2=0.f,a3=0.f;
  if (*flag) {
    const unsigned* X = (const unsigned*)x;
    for (int s = sc*64; s < sc*64+64; s++) {
      size_t bi = (((size_t)(b*Sq + s))*Dq + c0) >> 1;
      unsigned u0 = X[bi], u1 = X[bi+1];
      a0 += __uint_as_float(u0 << 16);
      a1 += __uint_as_float(u0 & 0xFFFF0000u);
      a2 += __uint_as_float(u1 << 16);
      a3 += __uint_as_float(u1 & 0xFFFF0000u);
    }
  } else {
    const float* X = (const float*)x;
    for (int s = sc*64; s < sc*64+64; s++) {
      float4 v = *(const float4*)&X[((size_t)(b*Sq + s))*Dq + c0];
      a0 += v.x; a1 += v.y; a2 += v.z; a3 += v.w;
    }
  }
  atomicAdd(&avgsum[b*Dq + c0 + 0], a0);
  atomicAdd(&avgsum[b*Dq + c0 + 1], a1);
  atomicAdd(&avgsum[b*Dq + c0 + 2], a2);
  atomicAdd(&avgsum[b*Dq + c0 + 3], a3);
}

// ---------------- gate dots (one wave per 1024-length dot) ----------------
template<typename IT>
__device__ void gdots_body(const float* __restrict__ avgs,
    const IT* __restrict__ w1, const IT* __restrict__ b1,
    const IT* __restrict__ taw, const IT* __restrict__ tab,
    const IT* __restrict__ agw, const IT* __restrict__ agb,
    float* __restrict__ g1b, float* __restrict__ lgb)
{
  int blk = blockIdx.x;
  int tid = threadIdx.x, lane = tid & 63, wave = tid >> 6;
  if (blk < 64) {
    int o = blk*4 + wave;
    int bb = o >> 7, j = o & 127;
    const float* av = avgs + bb*Dq;
    float a = 0.f;
#pragma unroll
    for (int k = 0; k < 16; k++) {
      int dd = k*64 + lane;
      a += av[dd] * toF(w1[dd*GATEq + j]);
    }
#pragma unroll
    for (int off=32; off>=1; off>>=1) a += __shfl_xor(a, off);
    if (lane == 0) g1b[o] = gelu_f(a*(1.f/(float)Sq) + toF(b1[j]));
  } else {
    int bb = wave >> 1, c = wave & 1;
    const float* av = avgs + bb*Dq;
    const IT* wm = (blk == 64) ? taw : agw;
    const IT* bm = (blk == 64) ? tab : agb;
    float a = 0.f;
#pragma unroll
    for (int k = 0; k < 16; k++) {
      int dd = k*64 + lane;
      a += av[dd] * toF(wm[dd*2 + c]);
    }
#pragma unroll
    for (int off=32; off>=1; off>>=1) a += __shfl_xor(a, off);
    if (lane == 0) lgb[(blk-64)*4 + wave] = a*(1.f/(float)Sq) + toF(bm[c]);
  }
}
__global__ __launch_bounds__(256)
void gate_dots_kernel(const int* __restrict__ flag, const float* avgs,
    const void* w1, const void* b1, const void* taw, const void* tab,
    const void* agw, const void* agb, float* g1b, float* lgb)
{
  if (*flag) gdots_body<bf16>(avgs, (const bf16*)w1,(const bf16*)b1,(const bf16*)taw,
      (const bf16*)tab,(const bf16*)agw,(const bf16*)agb, g1b, lgb);
  else gdots_body<float>(avgs, (const float*)w1,(const float*)b1,(const float*)taw,
      (const float*)tab,(const float*)agw,(const float*)agb, g1b, lgb);
}

// ---------------- gate finalize ----------------
template<typename IT>
__device__ void gfin_body(float* sh, const float* __restrict__ g1b, const float* __restrict__ lgb,
    const IT* __restrict__ w2, const IT* __restrict__ b2,
    float* __restrict__ cmb0, float* __restrict__ rs_tg0,
    float* __restrict__ rs_tg1, float* __restrict__ rs_ffn)
{
  int tid = threadIdx.x, lane = tid & 63, wave = tid >> 6;
  if (wave < 2) {
    float a = g1b[wave*128 + lane] * toF(w2[lane*2 + 1])
            + g1b[wave*128 + 64 + lane] * toF(w2[(64+lane)*2 + 1]);
#pragma unroll
    for (int off=32; off>=1; off>>=1) a += __shfl_xor(a, off);
    if (lane == 0) sh[wave] = 1.f/(1.f + __expf(-(a + toF(b2[1]))));
  }
  __syncthreads();
  if (tid < Bq) {
    int b = tid;
    float t0 = lgb[b*2], t1 = lgb[b*2+1];
    float m = fmaxf(t0,t1);
    float e0=__expf(t0-m), e1=__expf(t1-m), inv=1.f/(e0+e1);
    float tg0 = e0*inv, tg1 = e1*inv;
    float a0 = lgb[4+b*2], a1l = lgb[4+b*2+1];
    m = fmaxf(a0,a1l);
    float f0=__expf(a0-m), f1=__expf(a1l-m); inv = 1.f/(f0+f1);
    float ag0 = f0*inv, ag1 = f1*inv;
    cmb0[b] = ag0*DEPTHF;
    sh[2+b] = tg0*ag1*DEPTHF;
    sh[4+b] = tg1*ag1*DEPTHF;
    sh[6+b] = sh[b]*DEPTHF;
  }
  __syncthreads();
  for (int i = tid; i < BSq; i += 256) {
    int b = i >> 10;
    rs_tg0[i] = sh[2+b]; rs_tg1[i] = sh[4+b]; rs_ffn[i] = sh[6+b];
  }
}
__global__ __launch_bounds__(256)
void gate_fin_kernel(const int* __restrict__ flag, const float* g1b, const float* lgb,
    const void* w2, const void* b2, float* cmb0,
    float* rs_tg0, float* rs_tg1, float* rs_ffn)
{
  __shared__ float sh[8];
  if (*flag) gfin_body<bf16>(sh, g1b, lgb, (const bf16*)w2, (const bf16*)b2, cmb0, rs_tg0, rs_tg1, rs_ffn);
  else       gfin_body<float>(sh, g1b, lgb, (const float*)w2, (const float*)b2, cmb0, rs_tg0, rs_tg1, rs_ffn);
}

// ---------------- MoE router ----------------
template<typename IT>
__device__ void router_body(const IT* __restrict__ x, const IT* __restrict__ wr,
                            const IT* __restrict__ br, const float* __restrict__ cmb0,
                            float* __restrict__ gates_t)
{
  int row = blockIdx.x;
  int tid = threadIdx.x;
  size_t off = (size_t)row*Dq;
  float a0=0,a1=0,a2=0,a3=0;
  for (int dd = tid; dd < Dq; dd += 64) {
    float xv = toF(x[off+dd]);
    a0 += xv*toF(wr[dd*Eq+0]);
    a1 += xv*toF(wr[dd*Eq+1]);
    a2 += xv*toF(wr[dd*Eq+2]);
    a3 += xv*toF(wr[dd*Eq+3]);
  }
#pragma unroll
  for (int o=32;o>=1;o>>=1) {
    a0 += __shfl_xor(a0,o); a1 += __shfl_xor(a1,o);
    a2 += __shfl_xor(a2,o); a3 += __shfl_xor(a3,o);
  }
  if (tid == 0) {
    a0 += toF(br[0]); a1 += toF(br[1]); a2 += toF(br[2]); a3 += toF(br[3]);
    float m = fmaxf(fmaxf(a0,a1),fmaxf(a2,a3));
    float e0=__expf(a0-m), e1=__expf(a1-m), e2=__expf(a2-m), e3=__expf(a3-m);
    float inv = 1.f/(e0+e1+e2+e3);
    float sc = cmb0[row >> 10];
    gates_t[0*BSq+row]=e0*inv*sc; gates_t[1*BSq+row]=e1*inv*sc;
    gates_t[2*BSq+row]=e2*inv*sc; gates_t[3*BSq+row]=e3*inv*sc;
  }
}
__global__ __launch_bounds__(64)
void router_kernel(const int* __restrict__ flag, const void* x, const void* wr,
                   const void* br, const float* cmb0, float* gates_t)
{
  if (*flag) router_body<bf16>((const bf16*)x, (const bf16*)wr, (const bf16*)br, cmb0, gates_t);
  else       router_body<float>((const float*)x, (const float*)wr, (const float*)br, cmb0, gates_t);
}

extern "C" void kernel_launch(void* const* d_in, const int* in_sizes, int n_in,
                              void* d_out, int out_size, void* d_ws, size_t ws_size,
                              hipStream_t stream) {
  const void* x      = d_in[0];
  const void* arg_w1 = d_in[1];  const void* arg_b1 = d_in[2];
  const void* arg_w2 = d_in[3];  const void* arg_b2 = d_in[4];
  const void* moe_wr = d_in[5];  const void* moe_br = d_in[6];
  const void* moe_wq = d_in[7];  const void* moe_bq = d_in[8];
  const void* moe_wk = d_in[9];  const void* moe_bk = d_in[10];
  const void* moe_wv = d_in[11]; const void* moe_bv = d_in[12];
  const void* moe_wo = d_in[13]; const void* moe_bo = d_in[14];
  const void* sp_wq  = d_in[15]; const void* sp_bq  = d_in[16];
  const void* sp_wk  = d_in[17]; const void* sp_bk  = d_in[18];
  const void* sp_wv  = d_in[19]; const void* sp_bv  = d_in[20];
  const void* sp_wo  = d_in[21]; const void* sp_bo  = d_in[22];
  const void* pf_wq  = d_in[23]; const void* pf_bq  = d_in[24];
  const void* pf_wk  = d_in[25]; const void* pf_bk  = d_in[26];
  const void* pf_wv  = d_in[27]; const void* pf_bv  = d_in[28];
  const void* pf_wo  = d_in[29]; const void* pf_bo  = d_in[30];
  const void* pf_wf  = d_in[31];
  const void* taa_wg = d_in[32]; const void* taa_bg = d_in[33];
  const void* ag_w   = d_in[34]; const void* ag_b   = d_in[35];
  const void* ffn_w1 = d_in[36]; const void* ffn_b1 = d_in[37];
  const void* ffn_w2 = d_in[38]; const void* ffn_b2 = d_in[39];
  const void* n1_g   = d_in[40]; const void* n1_b   = d_in[41];
  const void* n2_g   = d_in[42]; const void* n2_b   = d_in[43];
  const void* n3_g   = d_in[44]; const void* n3_b   = d_in[45];

  char* w = (char*)d_ws;
  const size_t MB = 1024*1024;
  // phase 1 (attention):
  bf16* xb  = (bf16*)w;                 // [0,4)
  bf16* Qp  = (bf16*)(w + 4*MB);        // [4,28)  6 Q planes (attn out in place)
  bf16* KV  = (bf16*)(w + 28*MB);       // [28,44) K0,V0,K1,V1
  bf16* Vt  = (bf16*)(w + 44*MB);       // [44,52) Vt0,Vt1
  bf16* Pp  = (bf16*)(w + 28*MB);       // [28,52) 6 O-proj planes (over KV/Vt, dead)
  // phase 2 (FFN):
  bf16* x1    = (bf16*)(w + 4*MB);      // [4,8)
  bf16* ffn_h = (bf16*)(w + 8*MB);      // [8,24)
  float* partF= (float*)(w + 24*MB);    // [24,56) 4 f32 partial planes
  bf16* tmpb  = (bf16*)w;               // [0,4)  (xb dead)
  bf16* x2    = (bf16*)w;               // LN2 writes in place over tmpb (row-safe)
  // bookkeeping:
  char* book = w + 56*MB;
  float* rs_tg0 = (float*)book;
  float* rs_tg1 = rs_tg0 + BSq;
  float* rs_ffn = rs_tg1 + BSq;
  float* cmb0   = rs_ffn + BSq;
  float* avgp   = cmb0 + 16;
  float* gates_t= avgp + Bq*Dq;
  float* zb     = gates_t + Eq*BSq;
  float* g1b    = zb + Bq*Hq*Mq;
  float* lgb    = g1b + 256;
  int*   dflag  = (int*)(lgb + 8);
  bf16*  barena = (bf16*)(dflag + 16);
  bf16*  wft    = barena + 29696;
  bf16*  kvb    = (bf16*)(w + 57*MB);   // [57,58) performer kvT

  detect_kernel<<<1, 256, 0, stream>>>((const unsigned*)x, dflag);
  hipMemsetAsync(avgp, 0, (size_t)(Bq*Dq)*sizeof(float), stream);
  conv_x_kernel<<<BSq*Dq/1024, 256, 0, stream>>>(dflag, x, xb);
  pack_bias_kernel<<<1, 256, 0, stream>>>(dflag, barena,
      moe_bq, moe_bk, moe_bv, moe_bo, sp_bq, sp_bk, sp_bv, sp_bo,
      pf_bq, pf_bk, pf_bv, pf_bo, ffn_b1, ffn_b2);
  pack_wft_kernel<<<64, 256, 0, stream>>>(dflag, pf_wf, wft);
  avg2_kernel<<<Bq*16, 256, 0, stream>>>(dflag, x, avgp);
  gate_dots_kernel<<<66, 256, 0, stream>>>(dflag, avgp, arg_w1, arg_b1,
      taa_wg, taa_bg, ag_w, ag_b, g1b, lgb);
  gate_fin_kernel<<<1, 256, 0, stream>>>(dflag, g1b, lgb, arg_w2, arg_b2,
      cmb0, rs_tg0, rs_tg1, rs_ffn);
  router_kernel<<<BSq, 64, 0, stream>>>(dflag, x, moe_wr, moe_br, cmb0, gates_t);

  dim3 g6(16, 8, 6);
  dim3 gVT(Bq*Hq, Sq/64, 2);
  int nAttnBlk = Bq*Hq*(Sq/16);

  // ---- MoE expert attentions, paired ----
  for (int p = 0; p < 2; p++) {
    int e0 = 2*p, e1 = 2*p + 1;
    gemm6_k<<<g6, 256, 0, stream>>>(dflag, xb, 0L,
        moe_wq, moe_wk, moe_wv, moe_wq, moe_wk, moe_wv,
        (long)e0*DD, (long)e0*DD, (long)e0*DD, (long)e1*DD, (long)e1*DD, (long)e1*DD,
        e0*1024, e0*1024+4096, e0*1024+8192, e1*1024, e1*1024+4096, e1*1024+8192,
        nullptr, nullptr, nullptr, nullptr, nullptr, nullptr,
        Qp + (size_t)e0*PLANE, KV, KV + PLANE,
        Qp + (size_t)e1*PLANE, KV + 2*PLANE, KV + 3*PLANE,
        barena, Dq, Dq);
    vtrans_kernel<<<gVT, 256, 0, stream>>>(KV + PLANE, (long)(2*PLANE), Vt, (long)PLANE);
    attn_kernel<0><<<nAttnBlk, 256, 0, stream>>>(Qp + (size_t)e0*PLANE, KV, Vt, Qp + (size_t)e0*PLANE);
    attn_kernel<0><<<nAttnBlk, 256, 0, stream>>>(Qp + (size_t)e1*PLANE, KV + 2*PLANE, Vt + PLANE, Qp + (size_t)e1*PLANE);
  }

  // ---- sparse + performer QKV, paired ----
  gemm6_k<<<g6, 256, 0, stream>>>(dflag, xb, 0L,
      sp_wq, sp_wk, sp_wv, pf_wq, pf_wk, pf_wv,
      0L, 0L, 0L, 0L, 0L, 0L,
      16384, 17408, 18432, 20480, 21504, 22528,
      nullptr, nullptr, nullptr, nullptr, nullptr, nullptr,
      Qp + 4*PLANE, KV, KV + PLANE,
      Qp + 5*PLANE, KV + 2*PLANE, KV + 3*PLANE,
      barena, Dq, Dq);
  vtrans_kernel<<<gVT, 256, 0, stream>>>(KV + PLANE, (long)(2*PLANE), Vt, (long)PLANE);
  attn_kernel<1><<<nAttnBlk, 256, 0, stream>>>(Qp + 4*PLANE, KV, Vt, Qp + 4*PLANE);
  {
    dim3 gKV1(Bq*Hq, 8);
    perf_kv_mfma<<<gKV1, 256, 0, stream>>>(KV + 2*PLANE, Vt + PLANE, wft, kvb, zb);
  }
  perf_out_mfma<<<Bq*Hq*16, 256, 0, stream>>>(Qp + 5*PLANE, wft, kvb, zb, Qp + 5*PLANE);

  // ---- all six O-projections in one launch, each to its own plane ----
  gemm6_k<<<g6, 256, 0, stream>>>(dflag, Qp, (long)PLANE,
      moe_wo, moe_wo, moe_wo, moe_wo, sp_wo, pf_wo,
      0L, (long)DD, (long)2*DD, (long)3*DD, 0L, 0L,
      12288, 13312, 14336, 15360, 19456, 23552,
      gates_t, gates_t + BSq, gates_t + 2*BSq, gates_t + 3*BSq, rs_tg0, rs_tg1,
      Pp, Pp + PLANE, Pp + 2*PLANE, Pp + 3*PLANE, Pp + 4*PLANE, Pp + 5*PLANE,
      barena, Dq, Dq);

  // ---- LN1: x + sum of 6 planes -> x1 ----
  ln_kernel<<<BSq, 256, 0, stream>>>(dflag, x, Pp, nullptr, n1_g, n1_b, x1, 3);

  // ---- FFN ----
  gemm1_k<<<dim3(16, 32, 1), 256, 0, stream>>>(dflag, x1, Dq, ffn_w1,
      barena, 24576, nullptr, ffn_h, nullptr, 0L, FFq, Dq, 1, 0);
  gemm1_k<<<dim3(16, 8, 4), 256, 0, stream>>>(dflag, ffn_h, FFq, ffn_w2,
      nullptr, 0, nullptr, nullptr, partF, (long)PLANE, Dq, 1024, 0, 1024);
  combine_ffn2<<<BSq*Dq/1024, 256, 0, stream>>>(partF, barena, rs_ffn, tmpb);

  // ---- LN2, LN3 ----
  ln_kernel<<<BSq, 256, 0, stream>>>(dflag, nullptr, x1, tmpb, n2_g, n2_b, x2, 1);
  ln_kernel<<<BSq, 256, 0, stream>>>(dflag, nullptr, x2, nullptr, n3_g, n3_b, d_out, 2);
}

// Round 7
// 1092.666 us; speedup vs baseline: 1.0039x; 1.0039x over previous
//
#include <hip/hip_runtime.h>
#include <hip/hip_bf16.h>
#include <math.h>

#define Bq 2
#define Sq 1024
#define Dq 1024
#define Hq 16
#define DHq 64
#define FFq 4096
#define Eq 4
#define Kq 64
#define Mq 256
#define GATEq 128
#define BSq (Bq*Sq)
#define DEPTHF 1.25f
#define SCALEF 0.125f
#define DD (Dq*Dq)
#define PLANE ((size_t)BSq*Dq)

typedef __hip_bfloat16 bf16;
typedef __attribute__((ext_vector_type(8))) __bf16 bf16x8;
typedef __attribute__((ext_vector_type(4))) float f32x4;

__device__ __forceinline__ float toF(float v){ return v; }
__device__ __forceinline__ float toF(bf16 v){ return __bfloat162float(v); }
__device__ __forceinline__ void stF(float* p, size_t i, float v){ p[i] = v; }
__device__ __forceinline__ void stF(bf16* p, size_t i, float v){ p[i] = __float2bfloat16(v); }
__device__ __forceinline__ float gelu_f(float x){
  const float c = 0.7978845608028654f;
  return 0.5f*x*(1.0f + tanhf(c*(x + 0.044715f*x*x*x)));
}
__device__ __forceinline__ unsigned short bfb(float f){
  bf16 h = __float2bfloat16(f);
  return *(unsigned short*)&h;
}
// inverse of the monotone uint map (uu = s<0 ? ~bits : bits|0x80000000)
__device__ __forceinline__ float thr_decode(unsigned c){
  unsigned ub = (c & 0x80000000u) ? (c & 0x7FFFFFFFu) : ~c;
  return __uint_as_float(ub);
}
// async global->LDS, 16B per lane; lds pointer must be wave-uniform (chunk base)
__device__ __forceinline__ void async_lds16(const void* g, void* lds) {
  __builtin_amdgcn_global_load_lds(
      (const __attribute__((address_space(1))) void*)(unsigned long long)(uintptr_t)g,
      (__attribute__((address_space(3))) void*)(unsigned)(uintptr_t)lds, 16, 0, 0);
}

// ---------------- dtype detector ----------------
__global__ __launch_bounds__(256)
void detect_kernel(const unsigned* __restrict__ xw, int* __restrict__ flag)
{
  __shared__ int cnt;
  if (threadIdx.x == 0) cnt = 0;
  __syncthreads();
  int c = 0;
  for (int i = threadIdx.x; i < 4096; i += 256) {
    unsigned e = (xw[i] >> 7) & 0xFFu;
    c += (e >= 0x70u && e <= 0x8Fu) ? 1 : 0;
  }
#pragma unroll
  for (int o = 32; o >= 1; o >>= 1) c += __shfl_xor(c, o);
  if ((threadIdx.x & 63) == 0) atomicAdd(&cnt, c);
  __syncthreads();
  if (threadIdx.x == 0) *flag = (cnt > 2048) ? 1 : 0;
}

// ---------------- convert x -> bf16 ----------------
__global__ __launch_bounds__(256)
void conv_x_kernel(const int* __restrict__ flag, const void* __restrict__ x, bf16* __restrict__ xb)
{
  int f = *flag;
  int i0 = (blockIdx.x*256 + threadIdx.x)*4;
  if (i0 >= BSq*Dq) return;
  if (f) {
    const bf16* s = (const bf16*)x;
#pragma unroll
    for (int k=0;k<4;k++) xb[i0+k] = s[i0+k];
  } else {
    const float* s = (const float*)x;
#pragma unroll
    for (int k=0;k<4;k++) xb[i0+k] = __float2bfloat16(s[i0+k]);
  }
}

// ---------------- pack all biases into bf16 arena ----------------
template<typename IT>
__device__ void packseg(bf16* dst, const IT* src, int len)
{
  for (int i = threadIdx.x; i < len; i += 256) dst[i] = __float2bfloat16(toF(src[i]));
}
__global__ __launch_bounds__(256)
void pack_bias_kernel(const int* __restrict__ flag, bf16* arena,
    const void* bq, const void* bk, const void* bv, const void* bo,
    const void* sq, const void* sk, const void* sv, const void* so,
    const void* pq, const void* pk, const void* pv, const void* po,
    const void* f1, const void* f2)
{
  int f = *flag;
  if (f) {
    packseg(arena+0,     (const bf16*)bq, 4096); packseg(arena+4096,  (const bf16*)bk, 4096);
    packseg(arena+8192,  (const bf16*)bv, 4096); packseg(arena+12288, (const bf16*)bo, 4096);
    packseg(arena+16384, (const bf16*)sq, 1024); packseg(arena+17408, (const bf16*)sk, 1024);
    packseg(arena+18432, (const bf16*)sv, 1024); packseg(arena+19456, (const bf16*)so, 1024);
    packseg(arena+20480, (const bf16*)pq, 1024); packseg(arena+21504, (const bf16*)pk, 1024);
    packseg(arena+22528, (const bf16*)pv, 1024); packseg(arena+23552, (const bf16*)po, 1024);
    packseg(arena+24576, (const bf16*)f1, 4096); packseg(arena+28672, (const bf16*)f2, 1024);
  } else {
    packseg(arena+0,     (const float*)bq, 4096); packseg(arena+4096,  (const float*)bk, 4096);
    packseg(arena+8192,  (const float*)bv, 4096); packseg(arena+12288, (const float*)bo, 4096);
    packseg(arena+16384, (const float*)sq, 1024); packseg(arena+17408, (const float*)sk, 1024);
    packseg(arena+18432, (const float*)sv, 1024); packseg(arena+19456, (const float*)so, 1024);
    packseg(arena+20480, (const float*)pq, 1024); packseg(arena+21504, (const float*)pk, 1024);
    packseg(arena+22528, (const float*)pv, 1024); packseg(arena+23552, (const float*)po, 1024);
    packseg(arena+24576, (const float*)f1, 4096); packseg(arena+28672, (const float*)f2, 1024);
  }
}

// ---------------- pack wf (DH x M) -> wfT (M x DH) bf16 ----------------
template<typename IT>
__device__ void packwft_body(const IT* __restrict__ wf, bf16* __restrict__ wft)
{
  int i = blockIdx.x*256 + threadIdx.x;
  if (i >= DHq*Mq) return;
  int d = i >> 8, m = i & 255;
  wft[m*DHq + d] = __float2bfloat16(toF(wf[(size_t)d*Mq + m]));
}
__global__ __launch_bounds__(256)
void pack_wft_kernel(const int* __restrict__ flag, const void* wf, bf16* wft)
{
  if (*flag) packwft_body<bf16>((const bf16*)wf, wft);
  else       packwft_body<float>((const float*)wf, wft);
}

// ---------------- pipelined MFMA GEMM core (2-phase, double-buffered LDS) ----------------
template<typename WT>
__device__ void gemm_core(bf16* As, unsigned* Bs,
    const bf16* __restrict__ A, int lda, const WT* __restrict__ W,
    const bf16* __restrict__ barena, int biasOff,
    const float* __restrict__ rowscale, bf16* __restrict__ C,
    float* __restrict__ Cf, int N, int K, int act)
{
  int tid = threadIdx.x;
  int lane = tid & 63, wave = tid >> 6;
  int wr = wave >> 1, wc = wave & 1;
  int bm = blockIdx.x * 128, bn = blockIdx.y * 128;

  int arow1 = wave*16 + (lane>>2);
  int akey = (arow1 >> 1) & 3;
  int acol = ((lane & 3) ^ akey) * 8;
  const bf16* aP1 = A + (size_t)(bm + arow1)*lda + acol;
  const bf16* aP2 = A + (size_t)(bm + arow1 + 64)*lda + acol;

  int kp = tid >> 4, nb8 = (tid & 15)*8;
  const WT* wP = W + (size_t)(2*kp)*N + bn + nb8;

  f32x4 acc[4][4];
#pragma unroll
  for (int i=0;i<4;i++)
#pragma unroll
    for (int j=0;j<4;j++) acc[i][j] = (f32x4){0.f,0.f,0.f,0.f};

  int m = lane & 15, q = lane >> 4;
  int akey2 = (m >> 1) & 3;
  int aq = (q ^ akey2) * 8;

  const int T = K >> 5;
  uint4 rwa, rwb, rwc, rwd;

  async_lds16(aP1, As + wave*512);
  async_lds16(aP2, As + (wave+4)*512);
  aP1 += 32; aP2 += 32;
  if constexpr (sizeof(WT) == 2) {
    rwa = *(const uint4*)wP;
    rwb = *(const uint4*)(wP + N);
  } else {
    const float* f0 = (const float*)wP;
    const float* f1 = (const float*)(wP + N);
    rwa = *(const uint4*)f0; rwb = *(const uint4*)(f0+4);
    rwc = *(const uint4*)f1; rwd = *(const uint4*)(f1+4);
  }
  wP += (size_t)32*N;

  for (int t = 0; t < T; t++) {
    int cur = t & 1;
    unsigned p[8];
    if constexpr (sizeof(WT) == 2) {
      p[0] = (rwa.x & 0xFFFFu) | (rwb.x << 16);  p[1] = (rwa.x >> 16) | (rwb.x & 0xFFFF0000u);
      p[2] = (rwa.y & 0xFFFFu) | (rwb.y << 16);  p[3] = (rwa.y >> 16) | (rwb.y & 0xFFFF0000u);
      p[4] = (rwa.z & 0xFFFFu) | (rwb.z << 16);  p[5] = (rwa.z >> 16) | (rwb.z & 0xFFFF0000u);
      p[6] = (rwa.w & 0xFFFFu) | (rwb.w << 16);  p[7] = (rwa.w >> 16) | (rwb.w & 0xFFFF0000u);
    } else {
      p[0] = (unsigned)bfb(__uint_as_float(rwa.x)) | ((unsigned)bfb(__uint_as_float(rwc.x)) << 16);
      p[1] = (unsigned)bfb(__uint_as_float(rwa.y)) | ((unsigned)bfb(__uint_as_float(rwc.y)) << 16);
      p[2] = (unsigned)bfb(__uint_as_float(rwa.z)) | ((unsigned)bfb(__uint_as_float(rwc.z)) << 16);
      p[3] = (unsigned)bfb(__uint_as_float(rwa.w)) | ((unsigned)bfb(__uint_as_float(rwc.w)) << 16);
      p[4] = (unsigned)bfb(__uint_as_float(rwb.x)) | ((unsigned)bfb(__uint_as_float(rwd.x)) << 16);
      p[5] = (unsigned)bfb(__uint_as_float(rwb.y)) | ((unsigned)bfb(__uint_as_float(rwd.y)) << 16);
      p[6] = (unsigned)bfb(__uint_as_float(rwb.z)) | ((unsigned)bfb(__uint_as_float(rwd.z)) << 16);
      p[7] = (unsigned)bfb(__uint_as_float(rwb.w)) | ((unsigned)bfb(__uint_as_float(rwd.w)) << 16);
    }
    unsigned* bD = Bs + cur*2112 + kp*132 + nb8;
    *(uint4*)(bD)     = make_uint4(p[0],p[1],p[2],p[3]);
    *(uint4*)(bD + 4) = make_uint4(p[4],p[5],p[6],p[7]);
    asm volatile("s_waitcnt vmcnt(0)" ::: "memory");
    __syncthreads();
    if (t + 1 < T) {
      bf16* asn = As + ((t+1)&1)*4096;
      async_lds16(aP1, asn + wave*512);
      async_lds16(aP2, asn + (wave+4)*512);
      aP1 += 32; aP2 += 32;
      if constexpr (sizeof(WT) == 2) {
        rwa = *(const uint4*)wP;
        rwb = *(const uint4*)(wP + N);
      } else {
        const float* f0 = (const float*)wP;
        const float* f1 = (const float*)(wP + N);
        rwa = *(const uint4*)f0; rwb = *(const uint4*)(f0+4);
        rwc = *(const uint4*)f1; rwd = *(const uint4*)(f1+4);
      }
      wP += (size_t)32*N;
    }
    const bf16* asc = As + cur*4096;
    const unsigned* bsc = Bs + cur*2112;
    bf16x8 av[4], bv[4];
#pragma unroll
    for (int i=0;i<4;i++)
      av[i] = *(const bf16x8*)&asc[(wr*64 + i*16 + m)*32 + aq];
#pragma unroll
    for (int j=0;j<4;j++) {
      int n = wc*64 + j*16 + m;
      unsigned b0 = bsc[(q*4+0)*132 + n];
      unsigned b1 = bsc[(q*4+1)*132 + n];
      unsigned b2 = bsc[(q*4+2)*132 + n];
      unsigned b3 = bsc[(q*4+3)*132 + n];
      uint4 bb = make_uint4(b0,b1,b2,b3);
      bv[j] = *(const bf16x8*)&bb;
    }
#pragma unroll
    for (int i=0;i<4;i++)
#pragma unroll
      for (int j=0;j<4;j++)
        acc[i][j] = __builtin_amdgcn_mfma_f32_16x16x32_bf16(av[i], bv[j], acc[i][j], 0, 0, 0);
  }

#pragma unroll
  for (int i=0;i<4;i++) {
    int row0 = bm + wr*64 + i*16 + q*4;
#pragma unroll
    for (int j=0;j<4;j++) {
      int col = bn + wc*64 + j*16 + m;
      float bvv = barena ? toF(barena[biasOff + col]) : 0.f;
#pragma unroll
      for (int r=0;r<4;r++) {
        size_t idx = (size_t)(row0 + r)*N + col;
        if (Cf) {
          Cf[idx] = acc[i][j][r];
        } else {
          float v = acc[i][j][r] + bvv;
          if (act) v = gelu_f(v);
          if (rowscale) v *= rowscale[row0 + r];
          C[idx] = __float2bfloat16(v);
        }
      }
    }
  }
}

// six-way z-batched GEMM (QKV pairs / all O-projections)
__global__ __launch_bounds__(256, 3)
void gemm6_k(const int* __restrict__ flag, const bf16* Abase, long az,
    const void* w0, const void* w1, const void* w2,
    const void* w3, const void* w4, const void* w5,
    long e0, long e1, long e2, long e3, long e4, long e5,
    int b0, int b1, int b2, int b3, int b4, int b5,
    const float* r0, const float* r1, const float* r2,
    const float* r3, const float* r4, const float* r5,
    bf16* c0, bf16* c1, bf16* c2, bf16* c3, bf16* c4, bf16* c5,
    const bf16* barena, int N, int K)
{
  __shared__ bf16 As[2*4096];
  __shared__ unsigned Bs[2*2112];
  int z = blockIdx.z;
  const void* Wp = (z==0)?w0:(z==1)?w1:(z==2)?w2:(z==3)?w3:(z==4)?w4:w5;
  long eo        = (z==0)?e0:(z==1)?e1:(z==2)?e2:(z==3)?e3:(z==4)?e4:e5;
  int bo         = (z==0)?b0:(z==1)?b1:(z==2)?b2:(z==3)?b3:(z==4)?b4:b5;
  const float* rs= (z==0)?r0:(z==1)?r1:(z==2)?r2:(z==3)?r3:(z==4)?r4:r5;
  bf16* C        = (z==0)?c0:(z==1)?c1:(z==2)?c2:(z==3)?c3:(z==4)?c4:c5;
  const bf16* A  = Abase + (size_t)z*az;
  if (*flag) gemm_core<bf16>(As, Bs, A, K, (const bf16*)Wp + eo, barena, bo, rs, C, nullptr, N, K, 0);
  else       gemm_core<float>(As, Bs, A, K, (const float*)Wp + eo, barena, bo, rs, C, nullptr, N, K, 0);
}

// single-matrix GEMM with optional split-K (z = K-chunk, f32 partial out)
__global__ __launch_bounds__(256, 3)
void gemm1_k(const int* __restrict__ flag, const bf16* A, int lda, const void* W,
             const bf16* barena, int biasOff, const float* rowscale,
             bf16* C, float* Cf, long cfz, int N, int K, int act, int kz)
{
  __shared__ bf16 As[2*4096];
  __shared__ unsigned Bs[2*2112];
  int z = blockIdx.z;
  const bf16* Az = A + (size_t)z*kz;
  long wo = (size_t)z*kz*N;
  float* Cfz = Cf ? (Cf + (size_t)z*cfz) : nullptr;
  if (*flag) gemm_core<bf16>(As, Bs, Az, lda, (const bf16*)W + wo, barena, biasOff, rowscale, C, Cfz, N, K, act);
  else       gemm_core<float>(As, Bs, Az, lda, (const float*)W + wo, barena, biasOff, rowscale, C, Cfz, N, K, act);
}

// ---------------- FFN2 split-K combine: out = (sum partials + bias) * rowscale ----------------
__global__ __launch_bounds__(256)
void combine_ffn2(const float* __restrict__ pf, const bf16* __restrict__ barena,
                  const float* __restrict__ rs, bf16* __restrict__ out)
{
  int i0 = (blockIdx.x*256 + threadIdx.x)*4;
  float4 s0 = *(const float4*)(pf + i0);
  float4 s1 = *(const float4*)(pf + PLANE + i0);
  float4 s2 = *(const float4*)(pf + 2*PLANE + i0);
  float4 s3 = *(const float4*)(pf + 3*PLANE + i0);
  int row = i0 >> 10, col = i0 & 1023;
  float r = rs[row];
  out[i0+0] = __float2bfloat16((s0.x+s1.x+s2.x+s3.x + toF(barena[28672+col+0])) * r);
  out[i0+1] = __float2bfloat16((s0.y+s1.y+s2.y+s3.y + toF(barena[28672+col+1])) * r);
  out[i0+2] = __float2bfloat16((s0.z+s1.z+s2.z+s3.z + toF(barena[28672+col+2])) * r);
  out[i0+3] = __float2bfloat16((s0.w+s1.w+s2.w+s3.w + toF(barena[28672+col+3])) * r);
}

// ---------------- V transpose: V(b,s,h,d) -> Vt(b,h,d,s), z-batched ----------------
__global__ __launch_bounds__(256)
void vtrans_kernel(const bf16* __restrict__ Vb, long vz, bf16* __restrict__ Vtb, long vtz)
{
  __shared__ bf16 t[64][72];
  const bf16* V = Vb + (size_t)blockIdx.z*vz;
  bf16* Vt = Vtb + (size_t)blockIdx.z*vtz;
  int bh = blockIdx.x;
  int sc_ = blockIdx.y;
  int b = bh >> 4, h = bh & 15;
  int tid = threadIdx.x;
  {
    int s = tid >> 2, dd = (tid & 3) * 16;
    const bf16* src = &V[((size_t)b*Sq + sc_*64 + s)*Dq + h*64 + dd];
    uint4 a0 = *(const uint4*)src;
    uint4 a1 = *(const uint4*)(src + 8);
    *(uint4*)&t[s][dd]     = a0;
    *(uint4*)&t[s][dd + 8] = a1;
  }
  __syncthreads();
  {
    int d = tid >> 2, sp = (tid & 3) * 16;
    unsigned short buf[16];
#pragma unroll
    for (int e = 0; e < 16; e++) {
      bf16 v = t[sp + e][d];
      buf[e] = *(unsigned short*)&v;
    }
    bf16* dst = &Vt[((size_t)bh*DHq + d)*Sq + sc_*64 + sp];
    *(uint4*)dst       = *(uint4*)&buf[0];
    *(uint4*)(dst + 8) = *(uint4*)&buf[8];
  }
}

// ---------------- R6: flash dense attention (online softmax, wave-independent) ----------------
// Each wave owns 16 q-rows x full S, no LDS, no barriers.
// Swapped QK^T: cT = mfma(A=K rows(s), B=Q(cols=q-rows)); D: col=lane&15=q-row, row=s-local.
// PV swapped:   oT = mfma(A=Vt rows(d), B=P^T(cols=q-rows, k=s)); B-frag built via 8 shfl.
__global__ __launch_bounds__(256)
void flash_attn_kernel(const bf16* __restrict__ Q, const bf16* __restrict__ K,
                       const bf16* __restrict__ Vt, bf16* __restrict__ O)
{
  int p_ = blockIdx.x;                       // 512 blocks
  int g_ = (p_ & 7)*4 + ((p_ >> 3) & 3);     // (b,h): 4 groups per XCD
  int blk = p_ >> 5;                         // 0..15 (64 q-rows each)
  int h = g_ & 15, b = g_ >> 4;
  int tid = threadIdx.x, lane = tid & 63, wave = tid >> 6;
  int m = lane & 15, q = lane >> 4;
  size_t base = ((size_t)b*Sq)*Dq + (size_t)h*DHq;
  int q0 = blk*64 + wave*16;

  // Q as B-frags (col = q-row m, k = d 0..63)
  const bf16* qrow = &Q[base + (size_t)(q0 + m)*Dq + q*8];
  bf16x8 bq0 = *(const bf16x8*)qrow;
  bf16x8 bq1 = *(const bf16x8*)(qrow + 32);

  const bf16* krow = K + base + (size_t)m*Dq + q*8;                  // s-row m (+c0 rows)
  const bf16* vrow = Vt + ((size_t)(b*Hq + h)*DHq + m)*Sq + q*8;     // d-row m (+dt*16 rows)

  f32x4 oc[4];
#pragma unroll
  for (int dt=0;dt<4;dt++) oc[dt] = (f32x4){0.f,0.f,0.f,0.f};
  float mrun = -1e30f, lrun = 0.f;

  int srcA = m + ((q & 1) << 5);   // lanes holding s-halves for this q's k-range
  int srcB = srcA + 16;
  bool hi = (q >= 2);

  for (int c0 = 0; c0 < Sq; c0 += 32) {
    // ---- QK^T swapped: 2 s-tiles of 16 ----
    const bf16* ka = krow + (size_t)c0*Dq;
    bf16x8 a00 = *(const bf16x8*)ka;
    bf16x8 a01 = *(const bf16x8*)(ka + 32);
    const bf16* kb = ka + (size_t)16*Dq;
    bf16x8 a10 = *(const bf16x8*)kb;
    bf16x8 a11 = *(const bf16x8*)(kb + 32);
    f32x4 c0t = (f32x4){0.f,0.f,0.f,0.f};
    c0t = __builtin_amdgcn_mfma_f32_16x16x32_bf16(a00, bq0, c0t, 0, 0, 0);
    c0t = __builtin_amdgcn_mfma_f32_16x16x32_bf16(a01, bq1, c0t, 0, 0, 0);
    f32x4 c1t = (f32x4){0.f,0.f,0.f,0.f};
    c1t = __builtin_amdgcn_mfma_f32_16x16x32_bf16(a10, bq0, c1t, 0, 0, 0);
    c1t = __builtin_amdgcn_mfma_f32_16x16x32_bf16(a11, bq1, c1t, 0, 0, 0);
#pragma unroll
    for (int r=0;r<4;r++) { c0t[r] *= SCALEF; c1t[r] *= SCALEF; }

    // ---- chunk max for q-col m (lane-local 8 + 2 shuffles) ----
    float cmax = fmaxf(fmaxf(fmaxf(c0t[0], c0t[1]), fmaxf(c0t[2], c0t[3])),
                       fmaxf(fmaxf(c1t[0], c1t[1]), fmaxf(c1t[2], c1t[3])));
    cmax = fmaxf(cmax, __shfl_xor(cmax, 16));
    cmax = fmaxf(cmax, __shfl_xor(cmax, 32));

    // ---- online rescale (wave-uniform guard) ----
    if (__any(cmax > mrun)) {
      float mnew = fmaxf(mrun, cmax);
      float alpha = __expf(mrun - mnew);
#pragma unroll
      for (int dt=0;dt<4;dt++)
#pragma unroll
        for (int r=0;r<4;r++) oc[dt][r] *= alpha;
      lrun *= alpha;
      mrun = mnew;
    }

    // ---- p = exp(s - m), lane-local partial sum ----
    float p0[4], p1[4];
#pragma unroll
    for (int r=0;r<4;r++) { p0[r] = __expf(c0t[r] - mrun); p1[r] = __expf(c1t[r] - mrun); }
    lrun += (p0[0]+p0[1]) + (p0[2]+p0[3]) + (p1[0]+p1[1]) + (p1[2]+p1[3]);

    // ---- pack p to bf16 dwords, assemble PV B-frag via shuffles ----
    unsigned d00 = (unsigned)bfb(p0[0]) | ((unsigned)bfb(p0[1]) << 16);
    unsigned d01 = (unsigned)bfb(p0[2]) | ((unsigned)bfb(p0[3]) << 16);
    unsigned d10 = (unsigned)bfb(p1[0]) | ((unsigned)bfb(p1[1]) << 16);
    unsigned d11 = (unsigned)bfb(p1[2]) | ((unsigned)bfb(p1[3]) << 16);
    unsigned X0 = __shfl(d00, srcA, 64);
    unsigned X1 = __shfl(d01, srcA, 64);
    unsigned X2 = __shfl(d00, srcB, 64);
    unsigned X3 = __shfl(d01, srcB, 64);
    unsigned Y0 = __shfl(d10, srcA, 64);
    unsigned Y1 = __shfl(d11, srcA, 64);
    unsigned Y2 = __shfl(d10, srcB, 64);
    unsigned Y3 = __shfl(d11, srcB, 64);
    uint4 bb = make_uint4(hi ? Y0 : X0, hi ? Y1 : X1, hi ? Y2 : X2, hi ? Y3 : X3);
    bf16x8 pb = *(const bf16x8*)&bb;

    // ---- PV: 4 d-tiles, k = 32 s ----
    const bf16* va = vrow + c0;
#pragma unroll
    for (int dt=0;dt<4;dt++) {
      bf16x8 av = *(const bf16x8*)&va[(size_t)(dt*16)*Sq];
      oc[dt] = __builtin_amdgcn_mfma_f32_16x16x32_bf16(av, pb, oc[dt], 0, 0, 0);
    }
  }

  // ---- final denominator (cross-q reduce) and store O (in-place safe) ----
  lrun += __shfl_xor(lrun, 16);
  lrun += __shfl_xor(lrun, 32);
  lrun = fmaxf(lrun, 1e-30f);
  float inv = 1.0f / lrun;
  bf16* orow = O + base + (size_t)(q0 + m)*Dq + q*4;
#pragma unroll
  for (int dt=0;dt<4;dt++) {
    unsigned w0 = (unsigned)bfb(oc[dt][0]*inv) | ((unsigned)bfb(oc[dt][1]*inv) << 16);
    unsigned w1 = (unsigned)bfb(oc[dt][2]*inv) | ((unsigned)bfb(oc[dt][3]*inv) << 16);
    *(uint2*)&orow[dt*16] = make_uint2(w0, w1);
  }
}

// ---------------- MFMA fused attention (exact top-K sparse; XCD-swizzled) ----------------
template<int SPARSE>
__global__ __launch_bounds__(256, 4)
void attn_kernel(const bf16* __restrict__ Q, const bf16* __restrict__ K,
                 const bf16* __restrict__ Vt, bf16* __restrict__ O)
{
  const int PAST = 1032;
  __shared__ bf16 pa[16*PAST];
  __shared__ float partA[64], partB[64];
  __shared__ int cntb[2][64];

  int p_ = blockIdx.x;
  int g_ = (p_ & 7)*4 + ((p_ >> 3) & 3);
  int rb = p_ >> 5;
  int h  = g_ & 15;
  int b  = g_ >> 4;
  int tid = threadIdx.x, lane = tid & 63, wave = tid >> 6;
  int m = lane & 15, q = lane >> 4;
  size_t base = ((size_t)b*Sq)*Dq + (size_t)h*DHq;
  int q0 = rb*16;

  const bf16* qrow = &Q[base + (size_t)(q0+m)*Dq + q*8];
  bf16x8 aq0 = *(const bf16x8*)qrow;
  bf16x8 aq1 = *(const bf16x8*)(qrow + 32);

  f32x4 cc[16];
#pragma unroll
  for (int t = 0; t < 16; t++) {
    int j0 = wave*256 + t*16;
    const bf16* kp = &K[base + (size_t)(j0+m)*Dq + q*8];
    bf16x8 b0 = *(const bf16x8*)kp;
    bf16x8 b1 = *(const bf16x8*)(kp + 32);
    f32x4 c = {0.f,0.f,0.f,0.f};
    c = __builtin_amdgcn_mfma_f32_16x16x32_bf16(aq0, b0, c, 0, 0, 0);
    c = __builtin_amdgcn_mfma_f32_16x16x32_bf16(aq1, b1, c, 0, 0, 0);
#pragma unroll
    for (int r=0;r<4;r++) c[r] *= SCALEF;
    cc[t] = c;
  }

  unsigned lo[4] = {0u,0u,0u,0u};
  if (SPARSE) {
    int cnt_cur[4] = {Sq, Sq, Sq, Sq};
    for (int bit = 31; bit >= 0; bit--) {
      int par = bit & 1;
      unsigned cand[4];
      float candf[4];
      int c4[4] = {0,0,0,0};
#pragma unroll
      for (int r=0;r<4;r++) {
        cand[r] = lo[r] | (1u << bit);
        candf[r] = thr_decode(cand[r]);
      }
#pragma unroll
      for (int t=0;t<16;t++)
#pragma unroll
        for (int r=0;r<4;r++) c4[r] += (cc[t][r] >= candf[r]) ? 1 : 0;
#pragma unroll
      for (int o=1;o<16;o<<=1)
#pragma unroll
        for (int r=0;r<4;r++) c4[r] += __shfl_xor(c4[r], o);
      if (m == 0) {
#pragma unroll
        for (int r=0;r<4;r++) cntb[par][wave*16 + q*4 + r] = c4[r];
      }
      __syncthreads();
      int done = 1;
#pragma unroll
      for (int r=0;r<4;r++) {
        int row = q*4 + r;
        int tot = cntb[par][row] + cntb[par][16+row] + cntb[par][32+row] + cntb[par][48+row];
        if (tot >= Kq) { lo[r] = cand[r]; cnt_cur[r] = tot; }
        done &= (cnt_cur[r] == Kq) ? 1 : 0;
      }
      done &= __shfl_xor(done, 16);
      done &= __shfl_xor(done, 32);
      if (done) break;
    }
  }

  float mrow[4];
#pragma unroll
  for (int r=0;r<4;r++) {
    float v = -1e30f;
#pragma unroll
    for (int t=0;t<16;t++) v = fmaxf(v, cc[t][r]);
#pragma unroll
    for (int o=1;o<16;o<<=1) v = fmaxf(v, __shfl_xor(v, o));
    mrow[r] = v;
  }
  if (m == 0) {
#pragma unroll
    for (int r=0;r<4;r++) partA[wave*16 + q*4 + r] = mrow[r];
  }
  __syncthreads();
#pragma unroll
  for (int r=0;r<4;r++) {
    int row = q*4 + r;
    mrow[r] = fmaxf(fmaxf(partA[row], partA[16+row]), fmaxf(partA[32+row], partA[48+row]));
  }

  float thrf[4];
  if (SPARSE) {
#pragma unroll
    for (int r=0;r<4;r++) {
      thrf[r] = (!(lo[r] & 0x80000000u) && lo[r] <= 0x007FFFFFu)
                    ? -INFINITY : thr_decode(lo[r]);
    }
  }
  float rsum[4] = {0.f,0.f,0.f,0.f};
#pragma unroll
  for (int t=0;t<16;t++) {
    int col = wave*256 + t*16 + m;
#pragma unroll
    for (int r=0;r<4;r++) {
      float p;
      if (SPARSE) p = (cc[t][r] >= thrf[r]) ? __expf(cc[t][r] - mrow[r]) : 0.f;
      else        p = __expf(cc[t][r] - mrow[r]);
      rsum[r] += p;
      pa[(q*4+r)*PAST + col] = __float2bfloat16(p);
    }
  }
#pragma unroll
  for (int r=0;r<4;r++)
#pragma unroll
    for (int o=1;o<16;o<<=1) rsum[r] += __shfl_xor(rsum[r], o);
  if (m == 0) {
#pragma unroll
    for (int r=0;r<4;r++) partB[wave*16 + q*4 + r] = rsum[r];
  }
  __syncthreads();
#pragma unroll
  for (int r=0;r<4;r++) {
    int row = q*4 + r;
    rsum[r] = partB[row] + partB[16+row] + partB[32+row] + partB[48+row];
    rsum[r] = fmaxf(rsum[r], 1e-30f);
  }

  const bf16* vtp = &Vt[((size_t)(b*Hq + h)*DHq + wave*16 + m)*Sq];
  f32x4 oc = {0.f,0.f,0.f,0.f};
#pragma unroll 8
  for (int ks = 0; ks < 32; ks++) {
    bf16x8 af = *(const bf16x8*)&pa[m*PAST + ks*32 + q*8];
    bf16x8 bv = *(const bf16x8*)&vtp[ks*32 + q*8];
    oc = __builtin_amdgcn_mfma_f32_16x16x32_bf16(af, bv, oc, 0, 0, 0);
  }
#pragma unroll
  for (int r=0;r<4;r++) {
    O[base + (size_t)(q0 + q*4 + r)*Dq + wave*16 + m] = __float2bfloat16(oc[r] / rsum[r]);
  }
}

// ---------------- performer pass 1 (MFMA) ----------------
__global__ __launch_bounds__(256)
void perf_kv_mfma(const bf16* __restrict__ Kb, const bf16* __restrict__ Vt,
                  const bf16* __restrict__ wft, bf16* __restrict__ kvb,
                  float* __restrict__ zg)
{
  __shared__ bf16 pbuf[4][32*40];
  __shared__ float kvred[4][64*32];
  __shared__ float zred[4][32];

  int bh = blockIdx.x;
  int mg = blockIdx.y;
  int b = bh >> 4, h = bh & 15;
  int tid = threadIdx.x, lane = tid & 63, wave = tid >> 6;
  int ml = lane & 15, q = lane >> 4;
  size_t kbase = ((size_t)b*Sq)*Dq + (size_t)h*DHq;
  const bf16* vtb = Vt + (size_t)bh*DHq*Sq;
  int sw0 = wave*256;
  bf16* pw = pbuf[wave];

  bf16x8 awf[2][2];
#pragma unroll
  for (int t=0;t<2;t++) {
    const bf16* p = &wft[(size_t)(mg*32 + t*16 + ml)*DHq + q*8];
    awf[t][0] = *(const bf16x8*)p;
    awf[t][1] = *(const bf16x8*)(p + 32);
  }

  f32x4 acc[4][2];
#pragma unroll
  for (int dt=0;dt<4;dt++)
#pragma unroll
    for (int t=0;t<2;t++) acc[dt][t] = (f32x4){0.f,0.f,0.f,0.f};
  float zacc[2][4] = {{0.f,0.f,0.f,0.f},{0.f,0.f,0.f,0.f}};

  for (int st = 0; st < 8; st++) {
    int s0 = sw0 + st*32;
    f32x4 pk[2][2];
#pragma unroll
    for (int sc=0;sc<2;sc++) {
      const bf16* kp = &Kb[kbase + (size_t)(s0 + sc*16 + ml)*Dq + q*8];
      bf16x8 b0 = *(const bf16x8*)kp;
      bf16x8 b1 = *(const bf16x8*)(kp + 32);
#pragma unroll
      for (int t=0;t<2;t++) {
        f32x4 c = (f32x4){0.f,0.f,0.f,0.f};
        c = __builtin_amdgcn_mfma_f32_16x16x32_bf16(awf[t][0], b0, c, 0, 0, 0);
        c = __builtin_amdgcn_mfma_f32_16x16x32_bf16(awf[t][1], b1, c, 0, 0, 0);
        pk[t][sc] = c;
      }
    }
#pragma unroll
    for (int t=0;t<2;t++)
#pragma unroll
      for (int sc=0;sc<2;sc++)
#pragma unroll
        for (int r=0;r<4;r++) {
          float v = fmaxf(pk[t][sc][r], 0.f);
          zacc[t][r] += v;
          pw[(t*16 + q*4 + r)*40 + sc*16 + ml] = __float2bfloat16(v);
        }
#pragma unroll
    for (int dt=0;dt<4;dt++) {
      bf16x8 av = *(const bf16x8*)&vtb[(size_t)(dt*16 + ml)*Sq + s0 + q*8];
#pragma unroll
      for (int t=0;t<2;t++) {
        bf16x8 bp = *(const bf16x8*)&pw[(t*16 + ml)*40 + q*8];
        acc[dt][t] = __builtin_amdgcn_mfma_f32_16x16x32_bf16(av, bp, acc[dt][t], 0, 0, 0);
      }
    }
  }

#pragma unroll
  for (int dt=0;dt<4;dt++)
#pragma unroll
    for (int t=0;t<2;t++)
#pragma unroll
      for (int r=0;r<4;r++)
        kvred[wave][(dt*16 + q*4 + r)*32 + t*16 + ml] = acc[dt][t][r];
#pragma unroll
  for (int t=0;t<2;t++)
#pragma unroll
    for (int r=0;r<4;r++) {
      float v = zacc[t][r];
#pragma unroll
      for (int o=1;o<16;o<<=1) v += __shfl_xor(v, o);
      if (ml == 0) zred[wave][t*16 + q*4 + r] = v;
    }
  __syncthreads();
  for (int p = tid; p < 2048; p += 256) {
    float s = kvred[0][p] + kvred[1][p] + kvred[2][p] + kvred[3][p];
    int d = p >> 5, mloc = p & 31;
    kvb[(size_t)bh*(DHq*Mq) + d*Mq + mg*32 + mloc] = __float2bfloat16(s);
  }
  if (tid < 32) {
    float s = zred[0][tid] + zred[1][tid] + zred[2][tid] + zred[3][tid];
    zg[bh*Mq + mg*32 + tid] = s;
  }
}

// ---------------- performer pass 2 (MFMA) ----------------
__global__ __launch_bounds__(256)
void perf_out_mfma(const bf16* __restrict__ Q, const bf16* __restrict__ wft,
                   const bf16* __restrict__ kvb, const float* __restrict__ zg,
                   bf16* __restrict__ O)
{
  const int PQST = 264;
  __shared__ bf16 pa2[64*PQST];
  __shared__ float zs[Mq];

  int blk = blockIdx.x;
  int sc_ = blk & 15;
  int bh  = blk >> 4;
  int b = bh >> 4, h = bh & 15;
  int tid = threadIdx.x, lane = tid & 63, wave = tid >> 6;
  int ml = lane & 15, q = lane >> 4;
  size_t base = ((size_t)b*Sq)*Dq + (size_t)h*DHq;
  int s0 = sc_*64;

  zs[tid] = zg[bh*Mq + tid];

  const bf16* qp = &Q[base + (size_t)(s0 + wave*16 + ml)*Dq + q*8];
  bf16x8 aq0 = *(const bf16x8*)qp;
  bf16x8 aq1 = *(const bf16x8*)(qp + 32);
  __syncthreads();

  f32x4 pq[16];
#pragma unroll
  for (int mt=0;mt<16;mt++) {
    const bf16* wp = &wft[(size_t)(mt*16 + ml)*DHq + q*8];
    bf16x8 b0 = *(const bf16x8*)wp;
    bf16x8 b1 = *(const bf16x8*)(wp + 32);
    f32x4 c = (f32x4){0.f,0.f,0.f,0.f};
    c = __builtin_amdgcn_mfma_f32_16x16x32_bf16(aq0, b0, c, 0, 0, 0);
    c = __builtin_amdgcn_mfma_f32_16x16x32_bf16(aq1, b1, c, 0, 0, 0);
    pq[mt] = c;
  }

  float den[4] = {1e-6f, 1e-6f, 1e-6f, 1e-6f};
#pragma unroll
  for (int mt=0;mt<16;mt++)
#pragma unroll
    for (int r=0;r<4;r++) {
      float v = fmaxf(pq[mt][r], 0.f);
      den[r] += v * zs[mt*16 + ml];
      pa2[(wave*16 + q*4 + r)*PQST + mt*16 + ml] = __float2bfloat16(v);
    }
#pragma unroll
  for (int r=0;r<4;r++)
#pragma unroll
    for (int o=1;o<16;o<<=1) den[r] += __shfl_xor(den[r], o);
  __syncthreads();

  const bf16* kvp = kvb + (size_t)bh*(DHq*Mq);
  f32x4 oc[4];
#pragma unroll
  for (int dt=0;dt<4;dt++) oc[dt] = (f32x4){0.f,0.f,0.f,0.f};
#pragma unroll
  for (int ks=0; ks<8; ks++) {
    bf16x8 ap = *(const bf16x8*)&pa2[(wave*16 + ml)*PQST + ks*32 + q*8];
#pragma unroll
    for (int dt=0;dt<4;dt++) {
      bf16x8 bk = *(const bf16x8*)&kvp[(size_t)(dt*16 + ml)*Mq + ks*32 + q*8];
      oc[dt] = __builtin_amdgcn_mfma_f32_16x16x32_bf16(ap, bk, oc[dt], 0, 0, 0);
    }
  }
#pragma unroll
  for (int dt=0;dt<4;dt++)
#pragma unroll
    for (int r=0;r<4;r++)
      O[base + (size_t)(s0 + wave*16 + q*4 + r)*Dq + dt*16 + ml] =
          __float2bfloat16(oc[dt][r] / den[r]);
}

// ---------------- LayerNorm ----------------
template<typename IT>
__device__ void ln_body(float* buf, float* red, const IT* __restrict__ xb,
                        const void* Ap, const void* Bp,
                        const IT* __restrict__ g, const IT* __restrict__ be,
                        void* out, int mode)
{
  int row = blockIdx.x;
  int tid = threadIdx.x;
  size_t off = (size_t)row*Dq;
  for (int dd = tid; dd < Dq; dd += 256) {
    float v;
    if (mode == 0)      v = toF(xb[off+dd]) + toF(((const bf16*)Ap)[off+dd]);
    else if (mode == 1) v = toF(((const bf16*)Ap)[off+dd]) + toF(((const bf16*)Bp)[off+dd]);
    else if (mode == 3) {
      const bf16* P = (const bf16*)Ap;
      v = toF(xb[off+dd]);
#pragma unroll
      for (int p=0;p<6;p++) v += toF(P[(size_t)p*PLANE + off + dd]);
    }
    else                v = toF(((const bf16*)Ap)[off+dd]);
    buf[dd] = v;
  }
  __syncthreads();
  float s = 0.f, q = 0.f;
  for (int dd = tid; dd < Dq; dd += 256) { float v = buf[dd]; s += v; q += v*v; }
#pragma unroll
  for (int o=32;o>=1;o>>=1) { s += __shfl_xor(s,o); q += __shfl_xor(q,o); }
  int w = tid >> 6;
  if ((tid & 63) == 0) { red[w] = s; red[4+w] = q; }
  __syncthreads();
  if (tid == 0) {
    float S1 = red[0]+red[1]+red[2]+red[3];
    float Q1 = red[4]+red[5]+red[6]+red[7];
    float mu = S1 / (float)Dq;
    float var = Q1 / (float)Dq - mu*mu;
    red[8] = mu; red[9] = rsqrtf(fmaxf(var, 0.f) + 1e-5f);
  }
  __syncthreads();
  float mu = red[8], inv = red[9];
  for (int dd = tid; dd < Dq; dd += 256) {
    float v = (buf[dd]-mu)*inv*toF(g[dd]) + toF(be[dd]);
    if (mode == 2) stF((IT*)out, off+dd, v);
    else           stF((bf16*)out, off+dd, v);
  }
}

__global__ __launch_bounds__(256)
void ln_kernel(const int* __restrict__ flag, const void* xb, const void* A, const void* Bv,
               const void* g, const void* be, void* out, int mode)
{
  __shared__ float buf[Dq];
  __shared__ float red[10];
  if (*flag) ln_body<bf16>(buf, red, (const bf16*)xb, A, Bv, (const bf16*)g, (const bf16*)be, out, mode);
  else       ln_body<float>(buf, red, (const float*)xb, A, Bv, (const float*)g, (const float*)be, out, mode);
}

// ---------------- avg over S (coalesced rows, atomic column partials; writes RAW SUMS) ----------------
__global__ __launch_bounds__(256)
void avg2_kernel(const int* __restrict__ flag, const void* __restrict__ x, float* __restrict__ avgsum)
{
  int b  = blockIdx.x >> 4;
  int sc = blockIdx.x & 15;
  int t = threadIdx.x;
  int c0 = t*4;
  float a0=0.f,a1=0.f,a2=0.f,a3=0.f;
  if (*flag) {
    const unsigned* X = (const unsigned*)x;
    for (int s = sc*64; s < sc*64+64; s++) {
      size_t bi = (((size_t)(b*Sq + s))*Dq + c0) >> 1;
      unsigned u0 = X[bi], u1 = X[bi+1];
      a0 += __uint_as_float(u0 << 16);
      a1 += __uint_as_float(u0 & 0xFFFF0000u);
      a2 += __uint_as_float(u1 << 16);
      a3 += __uint_as_float(u1 & 0xFFFF0000u);
    }
  } else {
    const float* X = (const float*)x;
    for (int s = sc*64; s < sc*64+64; s++) {
      float4 v = *(const float4*)&X[((size_t)(b*Sq + s))*Dq + c0];
      a0 += v.x; a1 += v.y; a2 += v.z; a3 += v.w;
    }
  }
  atomicAdd(&avgsum[b*Dq + c0 + 0], a0);
  atomicAdd(&avgsum[b*Dq + c0 + 1], a1);
  atomicAdd(&avgsum[b*Dq + c0 + 2], a2);
  atomicAdd(&avgsum[b*Dq + c0 + 3], a3);
}

// ---------------- gate dots (one wave per 1024-length dot) ----------------
template<typename IT>
__device__ void gdots_body(const float* __restrict__ avgs,
    const IT* __restrict__ w1, const IT* __restrict__ b1,
    const IT* __restrict__ taw, const IT* __restrict__ tab,
    const IT* __restrict__ agw, const IT* __restrict__ agb,
    float* __restrict__ g1b, float* __restrict__ lgb)
{
  int blk = blockIdx.x;
  int tid = threadIdx.x, lane = tid & 63, wave = tid >> 6;
  if (blk < 64) {
    int o = blk*4 + wave;
    int bb = o >> 7, j = o & 127;
    const float* av = avgs + bb*Dq;
    float a = 0.f;
#pragma unroll
    for (int k = 0; k < 16; k++) {
      int dd = k*64 + lane;
      a += av[dd] * toF(w1[dd*GATEq + j]);
    }
#pragma unroll
    for (int off=32; off>=1; off>>=1) a += __shfl_xor(a, off);
    if (lane == 0) g1b[o] = gelu_f(a*(1.f/(float)Sq) + toF(b1[j]));
  } else {
    int bb = wave >> 1, c = wave & 1;
    const float* av = avgs + bb*Dq;
    const IT* wm = (blk == 64) ? taw : agw;
    const IT* bm = (blk == 64) ? tab : agb;
    float a = 0.f;
#pragma unroll
    for (int k = 0; k < 16; k++) {
      int dd = k*64 + lane;
      a += av[dd] * toF(wm[dd*2 + c]);
    }
#pragma unroll
    for (int off=32; off>=1; off>>=1) a += __shfl_xor(a, off);
    if (lane == 0) lgb[(blk-64)*4 + wave] = a*(1.f/(float)Sq) + toF(bm[c]);
  }
}
__global__ __launch_bounds__(256)
void gate_dots_kernel(const int* __restrict__ flag, const float* avgs,
    const void* w1, const void* b1, const void* taw, const void* tab,
    const void* agw, const void* agb, float* g1b, float* lgb)
{
  if (*flag) gdots_body<bf16>(avgs, (const bf16*)w1,(const bf16*)b1,(const bf16*)taw,
      (const bf16*)tab,(const bf16*)agw,(const bf16*)agb, g1b, lgb);
  else gdots_body<float>(avgs, (const float*)w1,(const float*)b1,(const float*)taw,
      (const float*)tab,(const float*)agw,(const float*)agb, g1b, lgb);
}

// ---------------- gate finalize ----------------
template<typename IT>
__device__ void gfin_body(float* sh, const float* __restrict__ g1b, const float* __restrict__ lgb,
    const IT* __restrict__ w2, const IT* __restrict__ b2,
    float* __restrict__ cmb0, float* __restrict__ rs_tg0,
    float* __restrict__ rs_tg1, float* __restrict__ rs_ffn)
{
  int tid = threadIdx.x, lane = tid & 63, wave = tid >> 6;
  if (wave < 2) {
    float a = g1b[wave*128 + lane] * toF(w2[lane*2 + 1])
            + g1b[wave*128 + 64 + lane] * toF(w2[(64+lane)*2 + 1]);
#pragma unroll
    for (int off=32; off>=1; off>>=1) a += __shfl_xor(a, off);
    if (lane == 0) sh[wave] = 1.f/(1.f + __expf(-(a + toF(b2[1]))));
  }
  __syncthreads();
  if (tid < Bq) {
    int b = tid;
    float t0 = lgb[b*2], t1 = lgb[b*2+1];
    float m = fmaxf(t0,t1);
    float e0=__expf(t0-m), e1=__expf(t1-m), inv=1.f/(e0+e1);
    float tg0 = e0*inv, tg1 = e1*inv;
    float a0 = lgb[4+b*2], a1l = lgb[4+b*2+1];
    m = fmaxf(a0,a1l);
    float f0=__expf(a0-m), f1=__expf(a1l-m); inv = 1.f/(f0+f1);
    float ag0 = f0*inv, ag1 = f1*inv;
    cmb0[b] = ag0*DEPTHF;
    sh[2+b] = tg0*ag1*DEPTHF;
    sh[4+b] = tg1*ag1*DEPTHF;
    sh[6+b] = sh[b]*DEPTHF;
  }
  __syncthreads();
  for (int i = tid; i < BSq; i += 256) {
    int b = i >> 10;
    rs_tg0[i] = sh[2+b]; rs_tg1[i] = sh[4+b]; rs_ffn[i] = sh[6+b];
  }
}
__global__ __launch_bounds__(256)
void gate_fin_kernel(const int* __restrict__ flag, const float* g1b, const float* lgb,
    const void* w2, const void* b2, float* cmb0,
    float* rs_tg0, float* rs_tg1, float* rs_ffn)
{
  __shared__ float sh[8];
  if (*flag) gfin_body<bf16>(sh, g1b, lgb, (const bf16*)w2, (const bf16*)b2, cmb0, rs_tg0, rs_tg1, rs_ffn);
  else       gfin_body<float>(sh, g1b, lgb, (const float*)w2, (const float*)b2, cmb0, rs_tg0, rs_tg1, rs_ffn);
}

// ---------------- MoE router ----------------
template<typename IT>
__device__ void router_body(const IT* __restrict__ x, const IT* __restrict__ wr,
                            const IT* __restrict__ br, const float* __restrict__ cmb0,
                            float* __restrict__ gates_t)
{
  int row = blockIdx.x;
  int tid = threadIdx.x;
  size_t off = (size_t)row*Dq;
  float a0=0,a1=0,a2=0,a3=0;
  for (int dd = tid; dd < Dq; dd += 64) {
    float xv = toF(x[off+dd]);
    a0 += xv*toF(wr[dd*Eq+0]);
    a1 += xv*toF(wr[dd*Eq+1]);
    a2 += xv*toF(wr[dd*Eq+2]);
    a3 += xv*toF(wr[dd*Eq+3]);
  }
#pragma unroll
  for (int o=32;o>=1;o>>=1) {
    a0 += __shfl_xor(a0,o); a1 += __shfl_xor(a1,o);
    a2 += __shfl_xor(a2,o); a3 += __shfl_xor(a3,o);
  }
  if (tid == 0) {
    a0 += toF(br[0]); a1 += toF(br[1]); a2 += toF(br[2]); a3 += toF(br[3]);
    float m = fmaxf(fmaxf(a0,a1),fmaxf(a2,a3));
    float e0=__expf(a0-m), e1=__expf(a1-m), e2=__expf(a2-m), e3=__expf(a3-m);
    float inv = 1.f/(e0+e1+e2+e3);
    float sc = cmb0[row >> 10];
    gates_t[0*BSq+row]=e0*inv*sc; gates_t[1*BSq+row]=e1*inv*sc;
    gates_t[2*BSq+row]=e2*inv*sc; gates_t[3*BSq+row]=e3*inv*sc;
  }
}
__global__ __launch_bounds__(64)
void router_kernel(const int* __restrict__ flag, const void* x, const void* wr,
                   const void* br, const float* cmb0, float* gates_t)
{
  if (*flag) router_body<bf16>((const bf16*)x, (const bf16*)wr, (const bf16*)br, cmb0, gates_t);
  else       router_body<float>((const float*)x, (const float*)wr, (const float*)br, cmb0, gates_t);
}

extern "C" void kernel_launch(void* const* d_in, const int* in_sizes, int n_in,
                              void* d_out, int out_size, void* d_ws, size_t ws_size,
                              hipStream_t stream) {
  const void* x      = d_in[0];
  const void* arg_w1 = d_in[1];  const void* arg_b1 = d_in[2];
  const void* arg_w2 = d_in[3];  const void* arg_b2 = d_in[4];
  const void* moe_wr = d_in[5];  const void* moe_br = d_in[6];
  const void* moe_wq = d_in[7];  const void* moe_bq = d_in[8];
  const void* moe_wk = d_in[9];  const void* moe_bk = d_in[10];
  const void* moe_wv = d_in[11]; const void* moe_bv = d_in[12];
  const void* moe_wo = d_in[13]; const void* moe_bo = d_in[14];
  const void* sp_wq  = d_in[15]; const void* sp_bq  = d_in[16];
  const void* sp_wk  = d_in[17]; const void* sp_bk  = d_in[18];
  const void* sp_wv  = d_in[19]; const void* sp_bv  = d_in[20];
  const void* sp_wo  = d_in[21]; const void* sp_bo  = d_in[22];
  const void* pf_wq  = d_in[23]; const void* pf_bq  = d_in[24];
  const void* pf_wk  = d_in[25]; const void* pf_bk  = d_in[26];
  const void* pf_wv  = d_in[27]; const void* pf_bv  = d_in[28];
  const void* pf_wo  = d_in[29]; const void* pf_bo  = d_in[30];
  const void* pf_wf  = d_in[31];
  const void* taa_wg = d_in[32]; const void* taa_bg = d_in[33];
  const void* ag_w   = d_in[34]; const void* ag_b   = d_in[35];
  const void* ffn_w1 = d_in[36]; const void* ffn_b1 = d_in[37];
  const void* ffn_w2 = d_in[38]; const void* ffn_b2 = d_in[39];
  const void* n1_g   = d_in[40]; const void* n1_b   = d_in[41];
  const void* n2_g   = d_in[42]; const void* n2_b   = d_in[43];
  const void* n3_g   = d_in[44]; const void* n3_b   = d_in[45];

  char* w = (char*)d_ws;
  const size_t MB = 1024*1024;
  // phase 1 (attention):
  bf16* xb  = (bf16*)w;                 // [0,4)
  bf16* Qp  = (bf16*)(w + 4*MB);        // [4,28)  6 Q planes (attn out in place)
  bf16* KV  = (bf16*)(w + 28*MB);       // [28,44) K0,V0,K1,V1
  bf16* Vt  = (bf16*)(w + 44*MB);       // [44,52) Vt0,Vt1
  bf16* Pp  = (bf16*)(w + 28*MB);       // [28,52) 6 O-proj planes (over KV/Vt, dead)
  // phase 2 (FFN):
  bf16* x1    = (bf16*)(w + 4*MB);      // [4,8)
  bf16* ffn_h = (bf16*)(w + 8*MB);      // [8,24)
  float* partF= (float*)(w + 24*MB);    // [24,56) 4 f32 partial planes
  bf16* tmpb  = (bf16*)w;               // [0,4)  (xb dead)
  bf16* x2    = (bf16*)w;               // LN2 writes in place over tmpb (row-safe)
  // bookkeeping:
  char* book = w + 56*MB;
  float* rs_tg0 = (float*)book;
  float* rs_tg1 = rs_tg0 + BSq;
  float* rs_ffn = rs_tg1 + BSq;
  float* cmb0   = rs_ffn + BSq;
  float* avgp   = cmb0 + 16;
  float* gates_t= avgp + Bq*Dq;
  float* zb     = gates_t + Eq*BSq;
  float* g1b    = zb + Bq*Hq*Mq;
  float* lgb    = g1b + 256;
  int*   dflag  = (int*)(lgb + 8);
  bf16*  barena = (bf16*)(dflag + 16);
  bf16*  wft    = barena + 29696;
  bf16*  kvb    = (bf16*)(w + 57*MB);   // [57,58) performer kvT

  detect_kernel<<<1, 256, 0, stream>>>((const unsigned*)x, dflag);
  hipMemsetAsync(avgp, 0, (size_t)(Bq*Dq)*sizeof(float), stream);
  conv_x_kernel<<<BSq*Dq/1024, 256, 0, stream>>>(dflag, x, xb);
  pack_bias_kernel<<<1, 256, 0, stream>>>(dflag, barena,
      moe_bq, moe_bk, moe_bv, moe_bo, sp_bq, sp_bk, sp_bv, sp_bo,
      pf_bq, pf_bk, pf_bv, pf_bo, ffn_b1, ffn_b2);
  pack_wft_kernel<<<64, 256, 0, stream>>>(dflag, pf_wf, wft);
  avg2_kernel<<<Bq*16, 256, 0, stream>>>(dflag, x, avgp);
  gate_dots_kernel<<<66, 256, 0, stream>>>(dflag, avgp, arg_w1, arg_b1,
      taa_wg, taa_bg, ag_w, ag_b, g1b, lgb);
  gate_fin_kernel<<<1, 256, 0, stream>>>(dflag, g1b, lgb, arg_w2, arg_b2,
      cmb0, rs_tg0, rs_tg1, rs_ffn);
  router_kernel<<<BSq, 64, 0, stream>>>(dflag, x, moe_wr, moe_br, cmb0, gates_t);

  dim3 g6(16, 8, 6);
  dim3 gVT(Bq*Hq, Sq/64, 2);
  int nAttnBlk = Bq*Hq*(Sq/16);       // sparse attn (2048)
  int nFlashBlk = Bq*Hq*(Sq/64);      // flash dense (512)

  // ---- MoE expert attentions, paired ----
  for (int p = 0; p < 2; p++) {
    int e0 = 2*p, e1 = 2*p + 1;
    gemm6_k<<<g6, 256, 0, stream>>>(dflag, xb, 0L,
        moe_wq, moe_wk, moe_wv, moe_wq, moe_wk, moe_wv,
        (long)e0*DD, (long)e0*DD, (long)e0*DD, (long)e1*DD, (long)e1*DD, (long)e1*DD,
        e0*1024, e0*1024+4096, e0*1024+8192, e1*1024, e1*1024+4096, e1*1024+8192,
        nullptr, nullptr, nullptr, nullptr, nullptr, nullptr,
        Qp + (size_t)e0*PLANE, KV, KV + PLANE,
        Qp + (size_t)e1*PLANE, KV + 2*PLANE, KV + 3*PLANE,
        barena, Dq, Dq);
    vtrans_kernel<<<gVT, 256, 0, stream>>>(KV + PLANE, (long)(2*PLANE), Vt, (long)PLANE);
    flash_attn_kernel<<<nFlashBlk, 256, 0, stream>>>(Qp + (size_t)e0*PLANE, KV, Vt, Qp + (size_t)e0*PLANE);
    flash_attn_kernel<<<nFlashBlk, 256, 0, stream>>>(Qp + (size_t)e1*PLANE, KV + 2*PLANE, Vt + PLANE, Qp + (size_t)e1*PLANE);
  }

  // ---- sparse + performer QKV, paired ----
  gemm6_k<<<g6, 256, 0, stream>>>(dflag, xb, 0L,
      sp_wq, sp_wk, sp_wv, pf_wq, pf_wk, pf_wv,
      0L, 0L, 0L, 0L, 0L, 0L,
      16384, 17408, 18432, 20480, 21504, 22528,
      nullptr, nullptr, nullptr, nullptr, nullptr, nullptr,
      Qp + 4*PLANE, KV, KV + PLANE,
      Qp + 5*PLANE, KV + 2*PLANE, KV + 3*PLANE,
      barena, Dq, Dq);
  vtrans_kernel<<<gVT, 256, 0, stream>>>(KV + PLANE, (long)(2*PLANE), Vt, (long)PLANE);
  attn_kernel<1><<<nAttnBlk, 256, 0, stream>>>(Qp + 4*PLANE, KV, Vt, Qp + 4*PLANE);
  {
    dim3 gKV1(Bq*Hq, 8);
    perf_kv_mfma<<<gKV1, 256, 0, stream>>>(KV + 2*PLANE, Vt + PLANE, wft, kvb, zb);
  }
  perf_out_mfma<<<Bq*Hq*16, 256, 0, stream>>>(Qp + 5*PLANE, wft, kvb, zb, Qp + 5*PLANE);

  // ---- all six O-projections in one launch, each to its own plane ----
  gemm6_k<<<g6, 256, 0, stream>>>(dflag, Qp, (long)PLANE,
      moe_wo, moe_wo, moe_wo, moe_wo, sp_wo, pf_wo,
      0L, (long)DD, (long)2*DD, (long)3*DD, 0L, 0L,
      12288, 13312, 14336, 15360, 19456, 23552,
      gates_t, gates_t + BSq, gates_t + 2*BSq, gates_t + 3*BSq, rs_tg0, rs_tg1,
      Pp, Pp + PLANE, Pp + 2*PLANE, Pp + 3*PLANE, Pp + 4*PLANE, Pp + 5*PLANE,
      barena, Dq, Dq);

  // ---- LN1: x + sum of 6 planes -> x1 ----
  ln_kernel<<<BSq, 256, 0, stream>>>(dflag, x, Pp, nullptr, n1_g, n1_b, x1, 3);

  // ---- FFN ----
  gemm1_k<<<dim3(16, 32, 1), 256, 0, stream>>>(dflag, x1, Dq, ffn_w1,
      barena, 24576, nullptr, ffn_h, nullptr, 0L, FFq, Dq, 1, 0);
  gemm1_k<<<dim3(16, 8, 4), 256, 0, stream>>>(dflag, ffn_h, FFq, ffn_w2,
      nullptr, 0, nullptr, nullptr, partF, (long)PLANE, Dq, 1024, 0, 1024);
  combine_ffn2<<<BSq*Dq/1024, 256, 0, stream>>>(partF, barena, rs_ffn, tmpb);

  // ---- LN2, LN3 ----
  ln_kernel<<<BSq, 256, 0, stream>>>(dflag, nullptr, x1, tmpb, n2_g, n2_b, x2, 1);
  ln_kernel<<<BSq, 256, 0, stream>>>(dflag, nullptr, x2, nullptr, n3_g, n3_b, d_out, 2);
}

// Round 8
// 1091.504 us; speedup vs baseline: 1.0050x; 1.0011x over previous
//
#include <hip/hip_runtime.h>
#include <hip/hip_bf16.h>
#include <math.h>

#define Bq 2
#define Sq 1024
#define Dq 1024
#define Hq 16
#define DHq 64
#define FFq 4096
#define Eq 4
#define Kq 64
#define Mq 256
#define GATEq 128
#define BSq (Bq*Sq)
#define DEPTHF 1.25f
#define SCALEF 0.125f
#define DD (Dq*Dq)
#define PLANE ((size_t)BSq*Dq)

typedef __hip_bfloat16 bf16;
typedef __attribute__((ext_vector_type(8))) __bf16 bf16x8;
typedef __attribute__((ext_vector_type(4))) float f32x4;

__device__ __forceinline__ float toF(float v){ return v; }
__device__ __forceinline__ float toF(bf16 v){ return __bfloat162float(v); }
__device__ __forceinline__ void stF(float* p, size_t i, float v){ p[i] = v; }
__device__ __forceinline__ void stF(bf16* p, size_t i, float v){ p[i] = __float2bfloat16(v); }
__device__ __forceinline__ float gelu_f(float x){
  const float c = 0.7978845608028654f;
  return 0.5f*x*(1.0f + tanhf(c*(x + 0.044715f*x*x*x)));
}
__device__ __forceinline__ unsigned short bfb(float f){
  bf16 h = __float2bfloat16(f);
  return *(unsigned short*)&h;
}
// inverse of the monotone uint map (uu = s<0 ? ~bits : bits|0x80000000)
__device__ __forceinline__ float thr_decode(unsigned c){
  unsigned ub = (c & 0x80000000u) ? (c & 0x7FFFFFFFu) : ~c;
  return __uint_as_float(ub);
}
// async global->LDS, 16B per lane; lds pointer must be wave-uniform (chunk base)
__device__ __forceinline__ void async_lds16(const void* g, void* lds) {
  __builtin_amdgcn_global_load_lds(
      (const __attribute__((address_space(1))) void*)(unsigned long long)(uintptr_t)g,
      (__attribute__((address_space(3))) void*)(unsigned)(uintptr_t)lds, 16, 0, 0);
}

// ---------------- dtype detector ----------------
__global__ __launch_bounds__(256)
void detect_kernel(const unsigned* __restrict__ xw, int* __restrict__ flag)
{
  __shared__ int cnt;
  if (threadIdx.x == 0) cnt = 0;
  __syncthreads();
  int c = 0;
  for (int i = threadIdx.x; i < 4096; i += 256) {
    unsigned e = (xw[i] >> 7) & 0xFFu;
    c += (e >= 0x70u && e <= 0x8Fu) ? 1 : 0;
  }
#pragma unroll
  for (int o = 32; o >= 1; o >>= 1) c += __shfl_xor(c, o);
  if ((threadIdx.x & 63) == 0) atomicAdd(&cnt, c);
  __syncthreads();
  if (threadIdx.x == 0) *flag = (cnt > 2048) ? 1 : 0;
}

// ---------------- convert x -> bf16 ----------------
__global__ __launch_bounds__(256)
void conv_x_kernel(const int* __restrict__ flag, const void* __restrict__ x, bf16* __restrict__ xb)
{
  int f = *flag;
  int i0 = (blockIdx.x*256 + threadIdx.x)*4;
  if (i0 >= BSq*Dq) return;
  if (f) {
    const bf16* s = (const bf16*)x;
#pragma unroll
    for (int k=0;k<4;k++) xb[i0+k] = s[i0+k];
  } else {
    const float* s = (const float*)x;
#pragma unroll
    for (int k=0;k<4;k++) xb[i0+k] = __float2bfloat16(s[i0+k]);
  }
}

// ---------------- pack all biases into bf16 arena ----------------
template<typename IT>
__device__ void packseg(bf16* dst, const IT* src, int len)
{
  for (int i = threadIdx.x; i < len; i += 256) dst[i] = __float2bfloat16(toF(src[i]));
}
__global__ __launch_bounds__(256)
void pack_bias_kernel(const int* __restrict__ flag, bf16* arena,
    const void* bq, const void* bk, const void* bv, const void* bo,
    const void* sq, const void* sk, const void* sv, const void* so,
    const void* pq, const void* pk, const void* pv, const void* po,
    const void* f1, const void* f2)
{
  int f = *flag;
  if (f) {
    packseg(arena+0,     (const bf16*)bq, 4096); packseg(arena+4096,  (const bf16*)bk, 4096);
    packseg(arena+8192,  (const bf16*)bv, 4096); packseg(arena+12288, (const bf16*)bo, 4096);
    packseg(arena+16384, (const bf16*)sq, 1024); packseg(arena+17408, (const bf16*)sk, 1024);
    packseg(arena+18432, (const bf16*)sv, 1024); packseg(arena+19456, (const bf16*)so, 1024);
    packseg(arena+20480, (const bf16*)pq, 1024); packseg(arena+21504, (const bf16*)pk, 1024);
    packseg(arena+22528, (const bf16*)pv, 1024); packseg(arena+23552, (const bf16*)po, 1024);
    packseg(arena+24576, (const bf16*)f1, 4096); packseg(arena+28672, (const bf16*)f2, 1024);
  } else {
    packseg(arena+0,     (const float*)bq, 4096); packseg(arena+4096,  (const float*)bk, 4096);
    packseg(arena+8192,  (const float*)bv, 4096); packseg(arena+12288, (const float*)bo, 4096);
    packseg(arena+16384, (const float*)sq, 1024); packseg(arena+17408, (const float*)sk, 1024);
    packseg(arena+18432, (const float*)sv, 1024); packseg(arena+19456, (const float*)so, 1024);
    packseg(arena+20480, (const float*)pq, 1024); packseg(arena+21504, (const float*)pk, 1024);
    packseg(arena+22528, (const float*)pv, 1024); packseg(arena+23552, (const float*)po, 1024);
    packseg(arena+24576, (const float*)f1, 4096); packseg(arena+28672, (const float*)f2, 1024);
  }
}

// ---------------- pack wf (DH x M) -> wfT (M x DH) bf16 ----------------
template<typename IT>
__device__ void packwft_body(const IT* __restrict__ wf, bf16* __restrict__ wft)
{
  int i = blockIdx.x*256 + threadIdx.x;
  if (i >= DHq*Mq) return;
  int d = i >> 8, m = i & 255;
  wft[m*DHq + d] = __float2bfloat16(toF(wf[(size_t)d*Mq + m]));
}
__global__ __launch_bounds__(256)
void pack_wft_kernel(const int* __restrict__ flag, const void* wf, bf16* wft)
{
  if (*flag) packwft_body<bf16>((const bf16*)wf, wft);
  else       packwft_body<float>((const float*)wf, wft);
}

// ---------------- pipelined MFMA GEMM core (2-phase, double-buffered LDS) ----------------
template<typename WT>
__device__ void gemm_core(bf16* As, unsigned* Bs,
    const bf16* __restrict__ A, int lda, const WT* __restrict__ W,
    const bf16* __restrict__ barena, int biasOff,
    const float* __restrict__ rowscale, bf16* __restrict__ C,
    float* __restrict__ Cf, int N, int K, int act)
{
  int tid = threadIdx.x;
  int lane = tid & 63, wave = tid >> 6;
  int wr = wave >> 1, wc = wave & 1;
  int bm = blockIdx.x * 128, bn = blockIdx.y * 128;

  int arow1 = wave*16 + (lane>>2);
  int akey = (arow1 >> 1) & 3;
  int acol = ((lane & 3) ^ akey) * 8;
  const bf16* aP1 = A + (size_t)(bm + arow1)*lda + acol;
  const bf16* aP2 = A + (size_t)(bm + arow1 + 64)*lda + acol;

  int kp = tid >> 4, nb8 = (tid & 15)*8;
  const WT* wP = W + (size_t)(2*kp)*N + bn + nb8;

  f32x4 acc[4][4];
#pragma unroll
  for (int i=0;i<4;i++)
#pragma unroll
    for (int j=0;j<4;j++) acc[i][j] = (f32x4){0.f,0.f,0.f,0.f};

  int m = lane & 15, q = lane >> 4;
  int akey2 = (m >> 1) & 3;
  int aq = (q ^ akey2) * 8;

  const int T = K >> 5;
  uint4 rwa, rwb, rwc, rwd;

  async_lds16(aP1, As + wave*512);
  async_lds16(aP2, As + (wave+4)*512);
  aP1 += 32; aP2 += 32;
  if constexpr (sizeof(WT) == 2) {
    rwa = *(const uint4*)wP;
    rwb = *(const uint4*)(wP + N);
  } else {
    const float* f0 = (const float*)wP;
    const float* f1 = (const float*)(wP + N);
    rwa = *(const uint4*)f0; rwb = *(const uint4*)(f0+4);
    rwc = *(const uint4*)f1; rwd = *(const uint4*)(f1+4);
  }
  wP += (size_t)32*N;

  for (int t = 0; t < T; t++) {
    int cur = t & 1;
    unsigned p[8];
    if constexpr (sizeof(WT) == 2) {
      p[0] = (rwa.x & 0xFFFFu) | (rwb.x << 16);  p[1] = (rwa.x >> 16) | (rwb.x & 0xFFFF0000u);
      p[2] = (rwa.y & 0xFFFFu) | (rwb.y << 16);  p[3] = (rwa.y >> 16) | (rwb.y & 0xFFFF0000u);
      p[4] = (rwa.z & 0xFFFFu) | (rwb.z << 16);  p[5] = (rwa.z >> 16) | (rwb.z & 0xFFFF0000u);
      p[6] = (rwa.w & 0xFFFFu) | (rwb.w << 16);  p[7] = (rwa.w >> 16) | (rwb.w & 0xFFFF0000u);
    } else {
      p[0] = (unsigned)bfb(__uint_as_float(rwa.x)) | ((unsigned)bfb(__uint_as_float(rwc.x)) << 16);
      p[1] = (unsigned)bfb(__uint_as_float(rwa.y)) | ((unsigned)bfb(__uint_as_float(rwc.y)) << 16);
      p[2] = (unsigned)bfb(__uint_as_float(rwa.z)) | ((unsigned)bfb(__uint_as_float(rwc.z)) << 16);
      p[3] = (unsigned)bfb(__uint_as_float(rwa.w)) | ((unsigned)bfb(__uint_as_float(rwc.w)) << 16);
      p[4] = (unsigned)bfb(__uint_as_float(rwb.x)) | ((unsigned)bfb(__uint_as_float(rwd.x)) << 16);
      p[5] = (unsigned)bfb(__uint_as_float(rwb.y)) | ((unsigned)bfb(__uint_as_float(rwd.y)) << 16);
      p[6] = (unsigned)bfb(__uint_as_float(rwb.z)) | ((unsigned)bfb(__uint_as_float(rwd.z)) << 16);
      p[7] = (unsigned)bfb(__uint_as_float(rwb.w)) | ((unsigned)bfb(__uint_as_float(rwd.w)) << 16);
    }
    unsigned* bD = Bs + cur*2112 + kp*132 + nb8;
    *(uint4*)(bD)     = make_uint4(p[0],p[1],p[2],p[3]);
    *(uint4*)(bD + 4) = make_uint4(p[4],p[5],p[6],p[7]);
    asm volatile("s_waitcnt vmcnt(0)" ::: "memory");
    __syncthreads();
    if (t + 1 < T) {
      bf16* asn = As + ((t+1)&1)*4096;
      async_lds16(aP1, asn + wave*512);
      async_lds16(aP2, asn + (wave+4)*512);
      aP1 += 32; aP2 += 32;
      if constexpr (sizeof(WT) == 2) {
        rwa = *(const uint4*)wP;
        rwb = *(const uint4*)(wP + N);
      } else {
        const float* f0 = (const float*)wP;
        const float* f1 = (const float*)(wP + N);
        rwa = *(const uint4*)f0; rwb = *(const uint4*)(f0+4);
        rwc = *(const uint4*)f1; rwd = *(const uint4*)(f1+4);
      }
      wP += (size_t)32*N;
    }
    const bf16* asc = As + cur*4096;
    const unsigned* bsc = Bs + cur*2112;
    bf16x8 av[4], bv[4];
#pragma unroll
    for (int i=0;i<4;i++)
      av[i] = *(const bf16x8*)&asc[(wr*64 + i*16 + m)*32 + aq];
#pragma unroll
    for (int j=0;j<4;j++) {
      int n = wc*64 + j*16 + m;
      unsigned b0 = bsc[(q*4+0)*132 + n];
      unsigned b1 = bsc[(q*4+1)*132 + n];
      unsigned b2 = bsc[(q*4+2)*132 + n];
      unsigned b3 = bsc[(q*4+3)*132 + n];
      uint4 bb = make_uint4(b0,b1,b2,b3);
      bv[j] = *(const bf16x8*)&bb;
    }
#pragma unroll
    for (int i=0;i<4;i++)
#pragma unroll
      for (int j=0;j<4;j++)
        acc[i][j] = __builtin_amdgcn_mfma_f32_16x16x32_bf16(av[i], bv[j], acc[i][j], 0, 0, 0);
  }

#pragma unroll
  for (int i=0;i<4;i++) {
    int row0 = bm + wr*64 + i*16 + q*4;
#pragma unroll
    for (int j=0;j<4;j++) {
      int col = bn + wc*64 + j*16 + m;
      float bvv = barena ? toF(barena[biasOff + col]) : 0.f;
#pragma unroll
      for (int r=0;r<4;r++) {
        size_t idx = (size_t)(row0 + r)*N + col;
        if (Cf) {
          Cf[idx] = acc[i][j][r];
        } else {
          float v = acc[i][j][r] + bvv;
          if (act) v = gelu_f(v);
          if (rowscale) v *= rowscale[row0 + r];
          C[idx] = __float2bfloat16(v);
        }
      }
    }
  }
}

// six-way z-batched GEMM (QKV pairs / all O-projections)
__global__ __launch_bounds__(256, 3)
void gemm6_k(const int* __restrict__ flag, const bf16* Abase, long az,
    const void* w0, const void* w1, const void* w2,
    const void* w3, const void* w4, const void* w5,
    long e0, long e1, long e2, long e3, long e4, long e5,
    int b0, int b1, int b2, int b3, int b4, int b5,
    const float* r0, const float* r1, const float* r2,
    const float* r3, const float* r4, const float* r5,
    bf16* c0, bf16* c1, bf16* c2, bf16* c3, bf16* c4, bf16* c5,
    const bf16* barena, int N, int K)
{
  __shared__ bf16 As[2*4096];
  __shared__ unsigned Bs[2*2112];
  int z = blockIdx.z;
  const void* Wp = (z==0)?w0:(z==1)?w1:(z==2)?w2:(z==3)?w3:(z==4)?w4:w5;
  long eo        = (z==0)?e0:(z==1)?e1:(z==2)?e2:(z==3)?e3:(z==4)?e4:e5;
  int bo         = (z==0)?b0:(z==1)?b1:(z==2)?b2:(z==3)?b3:(z==4)?b4:b5;
  const float* rs= (z==0)?r0:(z==1)?r1:(z==2)?r2:(z==3)?r3:(z==4)?r4:r5;
  bf16* C        = (z==0)?c0:(z==1)?c1:(z==2)?c2:(z==3)?c3:(z==4)?c4:c5;
  const bf16* A  = Abase + (size_t)z*az;
  if (*flag) gemm_core<bf16>(As, Bs, A, K, (const bf16*)Wp + eo, barena, bo, rs, C, nullptr, N, K, 0);
  else       gemm_core<float>(As, Bs, A, K, (const float*)Wp + eo, barena, bo, rs, C, nullptr, N, K, 0);
}

// single-matrix GEMM with optional split-K (z = K-chunk, f32 partial out)
__global__ __launch_bounds__(256, 3)
void gemm1_k(const int* __restrict__ flag, const bf16* A, int lda, const void* W,
             const bf16* barena, int biasOff, const float* rowscale,
             bf16* C, float* Cf, long cfz, int N, int K, int act, int kz)
{
  __shared__ bf16 As[2*4096];
  __shared__ unsigned Bs[2*2112];
  int z = blockIdx.z;
  const bf16* Az = A + (size_t)z*kz;
  long wo = (size_t)z*kz*N;
  float* Cfz = Cf ? (Cf + (size_t)z*cfz) : nullptr;
  if (*flag) gemm_core<bf16>(As, Bs, Az, lda, (const bf16*)W + wo, barena, biasOff, rowscale, C, Cfz, N, K, act);
  else       gemm_core<float>(As, Bs, Az, lda, (const float*)W + wo, barena, biasOff, rowscale, C, Cfz, N, K, act);
}

// ---------------- FFN2 split-K combine: out = (sum partials + bias) * rowscale ----------------
__global__ __launch_bounds__(256)
void combine_ffn2(const float* __restrict__ pf, const bf16* __restrict__ barena,
                  const float* __restrict__ rs, bf16* __restrict__ out)
{
  int i0 = (blockIdx.x*256 + threadIdx.x)*4;
  float4 s0 = *(const float4*)(pf + i0);
  float4 s1 = *(const float4*)(pf + PLANE + i0);
  float4 s2 = *(const float4*)(pf + 2*PLANE + i0);
  float4 s3 = *(const float4*)(pf + 3*PLANE + i0);
  int row = i0 >> 10, col = i0 & 1023;
  float r = rs[row];
  out[i0+0] = __float2bfloat16((s0.x+s1.x+s2.x+s3.x + toF(barena[28672+col+0])) * r);
  out[i0+1] = __float2bfloat16((s0.y+s1.y+s2.y+s3.y + toF(barena[28672+col+1])) * r);
  out[i0+2] = __float2bfloat16((s0.z+s1.z+s2.z+s3.z + toF(barena[28672+col+2])) * r);
  out[i0+3] = __float2bfloat16((s0.w+s1.w+s2.w+s3.w + toF(barena[28672+col+3])) * r);
}

// ---------------- V transpose: V(b,s,h,d) -> Vt(b,h,d,s), z-batched ----------------
__global__ __launch_bounds__(256)
void vtrans_kernel(const bf16* __restrict__ Vb, long vz, bf16* __restrict__ Vtb, long vtz)
{
  __shared__ bf16 t[64][72];
  const bf16* V = Vb + (size_t)blockIdx.z*vz;
  bf16* Vt = Vtb + (size_t)blockIdx.z*vtz;
  int bh = blockIdx.x;
  int sc_ = blockIdx.y;
  int b = bh >> 4, h = bh & 15;
  int tid = threadIdx.x;
  {
    int s = tid >> 2, dd = (tid & 3) * 16;
    const bf16* src = &V[((size_t)b*Sq + sc_*64 + s)*Dq + h*64 + dd];
    uint4 a0 = *(const uint4*)src;
    uint4 a1 = *(const uint4*)(src + 8);
    *(uint4*)&t[s][dd]     = a0;
    *(uint4*)&t[s][dd + 8] = a1;
  }
  __syncthreads();
  {
    int d = tid >> 2, sp = (tid & 3) * 16;
    unsigned short buf[16];
#pragma unroll
    for (int e = 0; e < 16; e++) {
      bf16 v = t[sp + e][d];
      buf[e] = *(unsigned short*)&v;
    }
    bf16* dst = &Vt[((size_t)bh*DHq + d)*Sq + sc_*64 + sp];
    *(uint4*)dst       = *(uint4*)&buf[0];
    *(uint4*)(dst + 8) = *(uint4*)&buf[8];
  }
}

// ---------------- R8: flash dense attention v2 ----------------
// Block = 16 q-rows; 4 waves split KV (256 s each, 8 chunks of 32).
// Register-prefetched K (next chunk loaded before current chunk's compute);
// V loads issued under the softmax chain. One barrier: LDS combine of
// per-wave (m,l,O) partials -> exact softmax. Grid 2048 (8 blocks/CU).
__global__ __launch_bounds__(256)
void flash_attn_kernel(const bf16* __restrict__ Q, const bf16* __restrict__ K,
                       const bf16* __restrict__ Vt, bf16* __restrict__ O)
{
  __shared__ float ocs[4][16][68];   // [wave][qrow][d], pad 68
  __shared__ float mls[4][2][16];    // [wave][{m,l}][qrow]

  int p_ = blockIdx.x;                       // 2048 blocks
  int g_ = (p_ & 7)*4 + ((p_ >> 3) & 3);     // (b,h): 4 groups per XCD
  int qt = p_ >> 5;                          // 0..63 (16 q-rows each)
  int h = g_ & 15, b = g_ >> 4;
  int tid = threadIdx.x, lane = tid & 63, wave = tid >> 6;
  int m = lane & 15, q = lane >> 4;
  size_t base = ((size_t)b*Sq)*Dq + (size_t)h*DHq;
  int q0 = qt*16;

  // Q as B-frags (col = q-row m, k = d 0..63)
  const bf16* qrow = &Q[base + (size_t)(q0 + m)*Dq + q*8];
  bf16x8 bq0 = *(const bf16x8*)qrow;
  bf16x8 bq1 = *(const bf16x8*)(qrow + 32);

  int s00 = wave*256;                                                  // this wave's KV range
  const bf16* krow = K + base + (size_t)(s00 + m)*Dq + q*8;
  const bf16* vrow = Vt + ((size_t)(b*Hq + h)*DHq + m)*Sq + s00 + q*8;

  f32x4 oc[4];
#pragma unroll
  for (int dt=0;dt<4;dt++) oc[dt] = (f32x4){0.f,0.f,0.f,0.f};
  float mrun = -1e30f, lrun = 0.f;

  int srcA = m + ((q & 1) << 5);
  int srcB = srcA + 16;
  bool hi = (q >= 2);

  // preload chunk 0 K-frags
  bf16x8 ka00 = *(const bf16x8*)krow;
  bf16x8 ka01 = *(const bf16x8*)(krow + 32);
  bf16x8 ka10 = *(const bf16x8*)(krow + (size_t)16*Dq);
  bf16x8 ka11 = *(const bf16x8*)(krow + (size_t)16*Dq + 32);

  for (int c = 0; c < 8; c++) {
    // ---- prefetch next chunk's K (flies under this chunk's compute) ----
    bf16x8 kn00, kn01, kn10, kn11;
    if (c < 7) {
      const bf16* kn = krow + (size_t)(c+1)*32*Dq;
      kn00 = *(const bf16x8*)kn;
      kn01 = *(const bf16x8*)(kn + 32);
      kn10 = *(const bf16x8*)(kn + (size_t)16*Dq);
      kn11 = *(const bf16x8*)(kn + (size_t)16*Dq + 32);
    }
    // ---- QK^T swapped ----
    f32x4 c0t = (f32x4){0.f,0.f,0.f,0.f};
    c0t = __builtin_amdgcn_mfma_f32_16x16x32_bf16(ka00, bq0, c0t, 0, 0, 0);
    c0t = __builtin_amdgcn_mfma_f32_16x16x32_bf16(ka01, bq1, c0t, 0, 0, 0);
    f32x4 c1t = (f32x4){0.f,0.f,0.f,0.f};
    c1t = __builtin_amdgcn_mfma_f32_16x16x32_bf16(ka10, bq0, c1t, 0, 0, 0);
    c1t = __builtin_amdgcn_mfma_f32_16x16x32_bf16(ka11, bq1, c1t, 0, 0, 0);
    // ---- V loads now: latency hides under softmax chain ----
    const bf16* va = vrow + c*32;
    bf16x8 av0 = *(const bf16x8*)va;
    bf16x8 av1 = *(const bf16x8*)&va[(size_t)16*Sq];
    bf16x8 av2 = *(const bf16x8*)&va[(size_t)32*Sq];
    bf16x8 av3 = *(const bf16x8*)&va[(size_t)48*Sq];
#pragma unroll
    for (int r=0;r<4;r++) { c0t[r] *= SCALEF; c1t[r] *= SCALEF; }

    // ---- chunk max (lane-local 8 + 2 shuffles) ----
    float cmax = fmaxf(fmaxf(fmaxf(c0t[0], c0t[1]), fmaxf(c0t[2], c0t[3])),
                       fmaxf(fmaxf(c1t[0], c1t[1]), fmaxf(c1t[2], c1t[3])));
    cmax = fmaxf(cmax, __shfl_xor(cmax, 16));
    cmax = fmaxf(cmax, __shfl_xor(cmax, 32));

    // ---- online rescale (wave-uniform guard) ----
    if (__any(cmax > mrun)) {
      float mnew = fmaxf(mrun, cmax);
      float alpha = __expf(mrun - mnew);
#pragma unroll
      for (int dt=0;dt<4;dt++)
#pragma unroll
        for (int r=0;r<4;r++) oc[dt][r] *= alpha;
      lrun *= alpha;
      mrun = mnew;
    }

    // ---- p = exp(s - m), lane-local partial sum ----
    float p0[4], p1[4];
#pragma unroll
    for (int r=0;r<4;r++) { p0[r] = __expf(c0t[r] - mrun); p1[r] = __expf(c1t[r] - mrun); }
    lrun += (p0[0]+p0[1]) + (p0[2]+p0[3]) + (p1[0]+p1[1]) + (p1[2]+p1[3]);

    // ---- pack p to bf16 dwords, assemble PV B-frag via shuffles ----
    unsigned d00 = (unsigned)bfb(p0[0]) | ((unsigned)bfb(p0[1]) << 16);
    unsigned d01 = (unsigned)bfb(p0[2]) | ((unsigned)bfb(p0[3]) << 16);
    unsigned d10 = (unsigned)bfb(p1[0]) | ((unsigned)bfb(p1[1]) << 16);
    unsigned d11 = (unsigned)bfb(p1[2]) | ((unsigned)bfb(p1[3]) << 16);
    unsigned X0 = __shfl(d00, srcA, 64);
    unsigned X1 = __shfl(d01, srcA, 64);
    unsigned X2 = __shfl(d00, srcB, 64);
    unsigned X3 = __shfl(d01, srcB, 64);
    unsigned Y0 = __shfl(d10, srcA, 64);
    unsigned Y1 = __shfl(d11, srcA, 64);
    unsigned Y2 = __shfl(d10, srcB, 64);
    unsigned Y3 = __shfl(d11, srcB, 64);
    uint4 bb = make_uint4(hi ? Y0 : X0, hi ? Y1 : X1, hi ? Y2 : X2, hi ? Y3 : X3);
    bf16x8 pb = *(const bf16x8*)&bb;

    // ---- PV ----
    oc[0] = __builtin_amdgcn_mfma_f32_16x16x32_bf16(av0, pb, oc[0], 0, 0, 0);
    oc[1] = __builtin_amdgcn_mfma_f32_16x16x32_bf16(av1, pb, oc[1], 0, 0, 0);
    oc[2] = __builtin_amdgcn_mfma_f32_16x16x32_bf16(av2, pb, oc[2], 0, 0, 0);
    oc[3] = __builtin_amdgcn_mfma_f32_16x16x32_bf16(av3, pb, oc[3], 0, 0, 0);

    if (c < 7) { ka00 = kn00; ka01 = kn01; ka10 = kn10; ka11 = kn11; }
  }

  // ---- per-wave partials -> LDS ----
  lrun += __shfl_xor(lrun, 16);
  lrun += __shfl_xor(lrun, 32);
#pragma unroll
  for (int dt=0;dt<4;dt++)
    *(float4*)&ocs[wave][m][dt*16 + q*4] = (float4){oc[dt][0], oc[dt][1], oc[dt][2], oc[dt][3]};
  if (q == 0) { mls[wave][0][m] = mrun; mls[wave][1][m] = lrun; }
  __syncthreads();

  // ---- combine: thread t owns (qrow mm, 4 consecutive d) ----
  int mm = tid >> 4, d0 = (tid & 15) * 4;
  float m0 = mls[0][0][mm], m1 = mls[1][0][mm], m2 = mls[2][0][mm], m3 = mls[3][0][mm];
  float M = fmaxf(fmaxf(m0, m1), fmaxf(m2, m3));
  float a0 = __expf(m0 - M), a1 = __expf(m1 - M), a2 = __expf(m2 - M), a3 = __expf(m3 - M);
  float l = mls[0][1][mm]*a0 + mls[1][1][mm]*a1 + mls[2][1][mm]*a2 + mls[3][1][mm]*a3;
  l = fmaxf(l, 1e-30f);
  float inv = 1.0f / l;
  float4 o0 = *(const float4*)&ocs[0][mm][d0];
  float4 o1 = *(const float4*)&ocs[1][mm][d0];
  float4 o2 = *(const float4*)&ocs[2][mm][d0];
  float4 o3 = *(const float4*)&ocs[3][mm][d0];
  float r0 = (o0.x*a0 + o1.x*a1 + o2.x*a2 + o3.x*a3) * inv;
  float r1 = (o0.y*a0 + o1.y*a1 + o2.y*a2 + o3.y*a3) * inv;
  float r2 = (o0.z*a0 + o1.z*a1 + o2.z*a2 + o3.z*a3) * inv;
  float r3 = (o0.w*a0 + o1.w*a1 + o2.w*a2 + o3.w*a3) * inv;
  bf16* op = O + base + (size_t)(q0 + mm)*Dq + d0;
  unsigned w0 = (unsigned)bfb(r0) | ((unsigned)bfb(r1) << 16);
  unsigned w1 = (unsigned)bfb(r2) | ((unsigned)bfb(r3) << 16);
  *(uint2*)op = make_uint2(w0, w1);
}

// ---------------- MFMA fused attention (exact top-K sparse; XCD-swizzled) ----------------
template<int SPARSE>
__global__ __launch_bounds__(256, 4)
void attn_kernel(const bf16* __restrict__ Q, const bf16* __restrict__ K,
                 const bf16* __restrict__ Vt, bf16* __restrict__ O)
{
  const int PAST = 1032;
  __shared__ bf16 pa[16*PAST];
  __shared__ float partA[64], partB[64];
  __shared__ int cntb[2][64];

  int p_ = blockIdx.x;
  int g_ = (p_ & 7)*4 + ((p_ >> 3) & 3);
  int rb = p_ >> 5;
  int h  = g_ & 15;
  int b  = g_ >> 4;
  int tid = threadIdx.x, lane = tid & 63, wave = tid >> 6;
  int m = lane & 15, q = lane >> 4;
  size_t base = ((size_t)b*Sq)*Dq + (size_t)h*DHq;
  int q0 = rb*16;

  const bf16* qrow = &Q[base + (size_t)(q0+m)*Dq + q*8];
  bf16x8 aq0 = *(const bf16x8*)qrow;
  bf16x8 aq1 = *(const bf16x8*)(qrow + 32);

  f32x4 cc[16];
#pragma unroll
  for (int t = 0; t < 16; t++) {
    int j0 = wave*256 + t*16;
    const bf16* kp = &K[base + (size_t)(j0+m)*Dq + q*8];
    bf16x8 b0 = *(const bf16x8*)kp;
    bf16x8 b1 = *(const bf16x8*)(kp + 32);
    f32x4 c = {0.f,0.f,0.f,0.f};
    c = __builtin_amdgcn_mfma_f32_16x16x32_bf16(aq0, b0, c, 0, 0, 0);
    c = __builtin_amdgcn_mfma_f32_16x16x32_bf16(aq1, b1, c, 0, 0, 0);
#pragma unroll
    for (int r=0;r<4;r++) c[r] *= SCALEF;
    cc[t] = c;
  }

  unsigned lo[4] = {0u,0u,0u,0u};
  if (SPARSE) {
    int cnt_cur[4] = {Sq, Sq, Sq, Sq};
    for (int bit = 31; bit >= 0; bit--) {
      int par = bit & 1;
      unsigned cand[4];
      float candf[4];
      int c4[4] = {0,0,0,0};
#pragma unroll
      for (int r=0;r<4;r++) {
        cand[r] = lo[r] | (1u << bit);
        candf[r] = thr_decode(cand[r]);
      }
#pragma unroll
      for (int t=0;t<16;t++)
#pragma unroll
        for (int r=0;r<4;r++) c4[r] += (cc[t][r] >= candf[r]) ? 1 : 0;
#pragma unroll
      for (int o=1;o<16;o<<=1)
#pragma unroll
        for (int r=0;r<4;r++) c4[r] += __shfl_xor(c4[r], o);
      if (m == 0) {
#pragma unroll
        for (int r=0;r<4;r++) cntb[par][wave*16 + q*4 + r] = c4[r];
      }
      __syncthreads();
      int done = 1;
#pragma unroll
      for (int r=0;r<4;r++) {
        int row = q*4 + r;
        int tot = cntb[par][row] + cntb[par][16+row] + cntb[par][32+row] + cntb[par][48+row];
        if (tot >= Kq) { lo[r] = cand[r]; cnt_cur[r] = tot; }
        done &= (cnt_cur[r] == Kq) ? 1 : 0;
      }
      done &= __shfl_xor(done, 16);
      done &= __shfl_xor(done, 32);
      if (done) break;
    }
  }

  float mrow[4];
#pragma unroll
  for (int r=0;r<4;r++) {
    float v = -1e30f;
#pragma unroll
    for (int t=0;t<16;t++) v = fmaxf(v, cc[t][r]);
#pragma unroll
    for (int o=1;o<16;o<<=1) v = fmaxf(v, __shfl_xor(v, o));
    mrow[r] = v;
  }
  if (m == 0) {
#pragma unroll
    for (int r=0;r<4;r++) partA[wave*16 + q*4 + r] = mrow[r];
  }
  __syncthreads();
#pragma unroll
  for (int r=0;r<4;r++) {
    int row = q*4 + r;
    mrow[r] = fmaxf(fmaxf(partA[row], partA[16+row]), fmaxf(partA[32+row], partA[48+row]));
  }

  float thrf[4];
  if (SPARSE) {
#pragma unroll
    for (int r=0;r<4;r++) {
      thrf[r] = (!(lo[r] & 0x80000000u) && lo[r] <= 0x007FFFFFu)
                    ? -INFINITY : thr_decode(lo[r]);
    }
  }
  float rsum[4] = {0.f,0.f,0.f,0.f};
#pragma unroll
  for (int t=0;t<16;t++) {
    int col = wave*256 + t*16 + m;
#pragma unroll
    for (int r=0;r<4;r++) {
      float p;
      if (SPARSE) p = (cc[t][r] >= thrf[r]) ? __expf(cc[t][r] - mrow[r]) : 0.f;
      else        p = __expf(cc[t][r] - mrow[r]);
      rsum[r] += p;
      pa[(q*4+r)*PAST + col] = __float2bfloat16(p);
    }
  }
#pragma unroll
  for (int r=0;r<4;r++)
#pragma unroll
    for (int o=1;o<16;o<<=1) rsum[r] += __shfl_xor(rsum[r], o);
  if (m == 0) {
#pragma unroll
    for (int r=0;r<4;r++) partB[wave*16 + q*4 + r] = rsum[r];
  }
  __syncthreads();
#pragma unroll
  for (int r=0;r<4;r++) {
    int row = q*4 + r;
    rsum[r] = partB[row] + partB[16+row] + partB[32+row] + partB[48+row];
    rsum[r] = fmaxf(rsum[r], 1e-30f);
  }

  const bf16* vtp = &Vt[((size_t)(b*Hq + h)*DHq + wave*16 + m)*Sq];
  f32x4 oc = {0.f,0.f,0.f,0.f};
#pragma unroll 8
  for (int ks = 0; ks < 32; ks++) {
    bf16x8 af = *(const bf16x8*)&pa[m*PAST + ks*32 + q*8];
    bf16x8 bv = *(const bf16x8*)&vtp[ks*32 + q*8];
    oc = __builtin_amdgcn_mfma_f32_16x16x32_bf16(af, bv, oc, 0, 0, 0);
  }
#pragma unroll
  for (int r=0;r<4;r++) {
    O[base + (size_t)(q0 + q*4 + r)*Dq + wave*16 + m] = __float2bfloat16(oc[r] / rsum[r]);
  }
}

// ---------------- performer pass 1 (MFMA) ----------------
__global__ __launch_bounds__(256)
void perf_kv_mfma(const bf16* __restrict__ Kb, const bf16* __restrict__ Vt,
                  const bf16* __restrict__ wft, bf16* __restrict__ kvb,
                  float* __restrict__ zg)
{
  __shared__ bf16 pbuf[4][32*40];
  __shared__ float kvred[4][64*32];
  __shared__ float zred[4][32];

  int bh = blockIdx.x;
  int mg = blockIdx.y;
  int b = bh >> 4, h = bh & 15;
  int tid = threadIdx.x, lane = tid & 63, wave = tid >> 6;
  int ml = lane & 15, q = lane >> 4;
  size_t kbase = ((size_t)b*Sq)*Dq + (size_t)h*DHq;
  const bf16* vtb = Vt + (size_t)bh*DHq*Sq;
  int sw0 = wave*256;
  bf16* pw = pbuf[wave];

  bf16x8 awf[2][2];
#pragma unroll
  for (int t=0;t<2;t++) {
    const bf16* p = &wft[(size_t)(mg*32 + t*16 + ml)*DHq + q*8];
    awf[t][0] = *(const bf16x8*)p;
    awf[t][1] = *(const bf16x8*)(p + 32);
  }

  f32x4 acc[4][2];
#pragma unroll
  for (int dt=0;dt<4;dt++)
#pragma unroll
    for (int t=0;t<2;t++) acc[dt][t] = (f32x4){0.f,0.f,0.f,0.f};
  float zacc[2][4] = {{0.f,0.f,0.f,0.f},{0.f,0.f,0.f,0.f}};

  for (int st = 0; st < 8; st++) {
    int s0 = sw0 + st*32;
    f32x4 pk[2][2];
#pragma unroll
    for (int sc=0;sc<2;sc++) {
      const bf16* kp = &Kb[kbase + (size_t)(s0 + sc*16 + ml)*Dq + q*8];
      bf16x8 b0 = *(const bf16x8*)kp;
      bf16x8 b1 = *(const bf16x8*)(kp + 32);
#pragma unroll
      for (int t=0;t<2;t++) {
        f32x4 c = (f32x4){0.f,0.f,0.f,0.f};
        c = __builtin_amdgcn_mfma_f32_16x16x32_bf16(awf[t][0], b0, c, 0, 0, 0);
        c = __builtin_amdgcn_mfma_f32_16x16x32_bf16(awf[t][1], b1, c, 0, 0, 0);
        pk[t][sc] = c;
      }
    }
#pragma unroll
    for (int t=0;t<2;t++)
#pragma unroll
      for (int sc=0;sc<2;sc++)
#pragma unroll
        for (int r=0;r<4;r++) {
          float v = fmaxf(pk[t][sc][r], 0.f);
          zacc[t][r] += v;
          pw[(t*16 + q*4 + r)*40 + sc*16 + ml] = __float2bfloat16(v);
        }
#pragma unroll
    for (int dt=0;dt<4;dt++) {
      bf16x8 av = *(const bf16x8*)&vtb[(size_t)(dt*16 + ml)*Sq + s0 + q*8];
#pragma unroll
      for (int t=0;t<2;t++) {
        bf16x8 bp = *(const bf16x8*)&pw[(t*16 + ml)*40 + q*8];
        acc[dt][t] = __builtin_amdgcn_mfma_f32_16x16x32_bf16(av, bp, acc[dt][t], 0, 0, 0);
      }
    }
  }

#pragma unroll
  for (int dt=0;dt<4;dt++)
#pragma unroll
    for (int t=0;t<2;t++)
#pragma unroll
      for (int r=0;r<4;r++)
        kvred[wave][(dt*16 + q*4 + r)*32 + t*16 + ml] = acc[dt][t][r];
#pragma unroll
  for (int t=0;t<2;t++)
#pragma unroll
    for (int r=0;r<4;r++) {
      float v = zacc[t][r];
#pragma unroll
      for (int o=1;o<16;o<<=1) v += __shfl_xor(v, o);
      if (ml == 0) zred[wave][t*16 + q*4 + r] = v;
    }
  __syncthreads();
  for (int p = tid; p < 2048; p += 256) {
    float s = kvred[0][p] + kvred[1][p] + kvred[2][p] + kvred[3][p];
    int d = p >> 5, mloc = p & 31;
    kvb[(size_t)bh*(DHq*Mq) + d*Mq + mg*32 + mloc] = __float2bfloat16(s);
  }
  if (tid < 32) {
    float s = zred[0][tid] + zred[1][tid] + zred[2][tid] + zred[3][tid];
    zg[bh*Mq + mg*32 + tid] = s;
  }
}

// ---------------- performer pass 2 (MFMA) ----------------
__global__ __launch_bounds__(256)
void perf_out_mfma(const bf16* __restrict__ Q, const bf16* __restrict__ wft,
                   const bf16* __restrict__ kvb, const float* __restrict__ zg,
                   bf16* __restrict__ O)
{
  const int PQST = 264;
  __shared__ bf16 pa2[64*PQST];
  __shared__ float zs[Mq];

  int blk = blockIdx.x;
  int sc_ = blk & 15;
  int bh  = blk >> 4;
  int b = bh >> 4, h = bh & 15;
  int tid = threadIdx.x, lane = tid & 63, wave = tid >> 6;
  int ml = lane & 15, q = lane >> 4;
  size_t base = ((size_t)b*Sq)*Dq + (size_t)h*DHq;
  int s0 = sc_*64;

  zs[tid] = zg[bh*Mq + tid];

  const bf16* qp = &Q[base + (size_t)(s0 + wave*16 + ml)*Dq + q*8];
  bf16x8 aq0 = *(const bf16x8*)qp;
  bf16x8 aq1 = *(const bf16x8*)(qp + 32);
  __syncthreads();

  f32x4 pq[16];
#pragma unroll
  for (int mt=0;mt<16;mt++) {
    const bf16* wp = &wft[(size_t)(mt*16 + ml)*DHq + q*8];
    bf16x8 b0 = *(const bf16x8*)wp;
    bf16x8 b1 = *(const bf16x8*)(wp + 32);
    f32x4 c = (f32x4){0.f,0.f,0.f,0.f};
    c = __builtin_amdgcn_mfma_f32_16x16x32_bf16(aq0, b0, c, 0, 0, 0);
    c = __builtin_amdgcn_mfma_f32_16x16x32_bf16(aq1, b1, c, 0, 0, 0);
    pq[mt] = c;
  }

  float den[4] = {1e-6f, 1e-6f, 1e-6f, 1e-6f};
#pragma unroll
  for (int mt=0;mt<16;mt++)
#pragma unroll
    for (int r=0;r<4;r++) {
      float v = fmaxf(pq[mt][r], 0.f);
      den[r] += v * zs[mt*16 + ml];
      pa2[(wave*16 + q*4 + r)*PQST + mt*16 + ml] = __float2bfloat16(v);
    }
#pragma unroll
  for (int r=0;r<4;r++)
#pragma unroll
    for (int o=1;o<16;o<<=1) den[r] += __shfl_xor(den[r], o);
  __syncthreads();

  const bf16* kvp = kvb + (size_t)bh*(DHq*Mq);
  f32x4 oc[4];
#pragma unroll
  for (int dt=0;dt<4;dt++) oc[dt] = (f32x4){0.f,0.f,0.f,0.f};
#pragma unroll
  for (int ks=0; ks<8; ks++) {
    bf16x8 ap = *(const bf16x8*)&pa2[(wave*16 + ml)*PQST + ks*32 + q*8];
#pragma unroll
    for (int dt=0;dt<4;dt++) {
      bf16x8 bk = *(const bf16x8*)&kvp[(size_t)(dt*16 + ml)*Mq + ks*32 + q*8];
      oc[dt] = __builtin_amdgcn_mfma_f32_16x16x32_bf16(ap, bk, oc[dt], 0, 0, 0);
    }
  }
#pragma unroll
  for (int dt=0;dt<4;dt++)
#pragma unroll
    for (int r=0;r<4;r++)
      O[base + (size_t)(s0 + wave*16 + q*4 + r)*Dq + dt*16 + ml] =
          __float2bfloat16(oc[dt][r] / den[r]);
}

// ---------------- LayerNorm ----------------
template<typename IT>
__device__ void ln_body(float* buf, float* red, const IT* __restrict__ xb,
                        const void* Ap, const void* Bp,
                        const IT* __restrict__ g, const IT* __restrict__ be,
                        void* out, int mode)
{
  int row = blockIdx.x;
  int tid = threadIdx.x;
  size_t off = (size_t)row*Dq;
  for (int dd = tid; dd < Dq; dd += 256) {
    float v;
    if (mode == 0)      v = toF(xb[off+dd]) + toF(((const bf16*)Ap)[off+dd]);
    else if (mode == 1) v = toF(((const bf16*)Ap)[off+dd]) + toF(((const bf16*)Bp)[off+dd]);
    else if (mode == 3) {
      const bf16* P = (const bf16*)Ap;
      v = toF(xb[off+dd]);
#pragma unroll
      for (int p=0;p<6;p++) v += toF(P[(size_t)p*PLANE + off + dd]);
    }
    else                v = toF(((const bf16*)Ap)[off+dd]);
    buf[dd] = v;
  }
  __syncthreads();
  float s = 0.f, q = 0.f;
  for (int dd = tid; dd < Dq; dd += 256) { float v = buf[dd]; s += v; q += v*v; }
#pragma unroll
  for (int o=32;o>=1;o>>=1) { s += __shfl_xor(s,o); q += __shfl_xor(q,o); }
  int w = tid >> 6;
  if ((tid & 63) == 0) { red[w] = s; red[4+w] = q; }
  __syncthreads();
  if (tid == 0) {
    float S1 = red[0]+red[1]+red[2]+red[3];
    float Q1 = red[4]+red[5]+red[6]+red[7];
    float mu = S1 / (float)Dq;
    float var = Q1 / (float)Dq - mu*mu;
    red[8] = mu; red[9] = rsqrtf(fmaxf(var, 0.f) + 1e-5f);
  }
  __syncthreads();
  float mu = red[8], inv = red[9];
  for (int dd = tid; dd < Dq; dd += 256) {
    float v = (buf[dd]-mu)*inv*toF(g[dd]) + toF(be[dd]);
    if (mode == 2) stF((IT*)out, off+dd, v);
    else           stF((bf16*)out, off+dd, v);
  }
}

__global__ __launch_bounds__(256)
void ln_kernel(const int* __restrict__ flag, const void* xb, const void* A, const void* Bv,
               const void* g, const void* be, void* out, int mode)
{
  __shared__ float buf[Dq];
  __shared__ float red[10];
  if (*flag) ln_body<bf16>(buf, red, (const bf16*)xb, A, Bv, (const bf16*)g, (const bf16*)be, out, mode);
  else       ln_body<float>(buf, red, (const float*)xb, A, Bv, (const float*)g, (const float*)be, out, mode);
}

// ---------------- avg over S (coalesced rows, atomic column partials; writes RAW SUMS) ----------------
__global__ __launch_bounds__(256)
void avg2_kernel(const int* __restrict__ flag, const void* __restrict__ x, float* __restrict__ avgsum)
{
  int b  = blockIdx.x >> 4;
  int sc = blockIdx.x & 15;
  int t = threadIdx.x;
  int c0 = t*4;
  float a0=0.f,a1=0.f,a2=0.f,a3=0.f;
  if (*flag) {
    const unsigned* X = (const unsigned*)x;
    for (int s = sc*64; s < sc*64+64; s++) {
      size_t bi = (((size_t)(b*Sq + s))*Dq + c0) >> 1;
      unsigned u0 = X[bi], u1 = X[bi+1];
      a0 += __uint_as_float(u0 << 16);
      a1 += __uint_as_float(u0 & 0xFFFF0000u);
      a2 += __uint_as_float(u1 << 16);
      a3 += __uint_as_float(u1 & 0xFFFF0000u);
    }
  } else {
    const float* X = (const float*)x;
    for (int s = sc*64; s < sc*64+64; s++) {
      float4 v = *(const float4*)&X[((size_t)(b*Sq + s))*Dq + c0];
      a0 += v.x; a1 += v.y; a2 += v.z; a3 += v.w;
    }
  }
  atomicAdd(&avgsum[b*Dq + c0 + 0], a0);
  atomicAdd(&avgsum[b*Dq + c0 + 1], a1);
  atomicAdd(&avgsum[b*Dq + c0 + 2], a2);
  atomicAdd(&avgsum[b*Dq + c0 + 3], a3);
}

// ---------------- gate dots (one wave per 1024-length dot) ----------------
template<typename IT>
__device__ void gdots_body(const float* __restrict__ avgs,
    const IT* __restrict__ w1, const IT* __restrict__ b1,
    const IT* __restrict__ taw, const IT* __restrict__ tab,
    const IT* __restrict__ agw, const IT* __restrict__ agb,
    float* __restrict__ g1b, float* __restrict__ lgb)
{
  int blk = blockIdx.x;
  int tid = threadIdx.x, lane = tid & 63, wave = tid >> 6;
  if (blk < 64) {
    int o = blk*4 + wave;
    int bb = o >> 7, j = o & 127;
    const float* av = avgs + bb*Dq;
    float a = 0.f;
#pragma unroll
    for (int k = 0; k < 16; k++) {
      int dd = k*64 + lane;
      a += av[dd] * toF(w1[dd*GATEq + j]);
    }
#pragma unroll
    for (int off=32; off>=1; off>>=1) a += __shfl_xor(a, off);
    if (lane == 0) g1b[o] = gelu_f(a*(1.f/(float)Sq) + toF(b1[j]));
  } else {
    int bb = wave >> 1, c = wave & 1;
    const float* av = avgs + bb*Dq;
    const IT* wm = (blk == 64) ? taw : agw;
    const IT* bm = (blk == 64) ? tab : agb;
    float a = 0.f;
#pragma unroll
    for (int k = 0; k < 16; k++) {
      int dd = k*64 + lane;
      a += av[dd] * toF(wm[dd*2 + c]);
    }
#pragma unroll
    for (int off=32; off>=1; off>>=1) a += __shfl_xor(a, off);
    if (lane == 0) lgb[(blk-64)*4 + wave] = a*(1.f/(float)Sq) + toF(bm[c]);
  }
}
__global__ __launch_bounds__(256)
void gate_dots_kernel(const int* __restrict__ flag, const float* avgs,
    const void* w1, const void* b1, const void* taw, const void* tab,
    const void* agw, const void* agb, float* g1b, float* lgb)
{
  if (*flag) gdots_body<bf16>(avgs, (const bf16*)w1,(const bf16*)b1,(const bf16*)taw,
      (const bf16*)tab,(const bf16*)agw,(const bf16*)agb, g1b, lgb);
  else gdots_body<float>(avgs, (const float*)w1,(const float*)b1,(const float*)taw,
      (const float*)tab,(const float*)agw,(const float*)agb, g1b, lgb);
}

// ---------------- gate finalize ----------------
template<typename IT>
__device__ void gfin_body(float* sh, const float* __restrict__ g1b, const float* __restrict__ lgb,
    const IT* __restrict__ w2, const IT* __restrict__ b2,
    float* __restrict__ cmb0, float* __restrict__ rs_tg0,
    float* __restrict__ rs_tg1, float* __restrict__ rs_ffn)
{
  int tid = threadIdx.x, lane = tid & 63, wave = tid >> 6;
  if (wave < 2) {
    float a = g1b[wave*128 + lane] * toF(w2[lane*2 + 1])
            + g1b[wave*128 + 64 + lane] * toF(w2[(64+lane)*2 + 1]);
#pragma unroll
    for (int off=32; off>=1; off>>=1) a += __shfl_xor(a, off);
    if (lane == 0) sh[wave] = 1.f/(1.f + __expf(-(a + toF(b2[1]))));
  }
  __syncthreads();
  if (tid < Bq) {
    int b = tid;
    float t0 = lgb[b*2], t1 = lgb[b*2+1];
    float m = fmaxf(t0,t1);
    float e0=__expf(t0-m), e1=__expf(t1-m), inv=1.f/(e0+e1);
    float tg0 = e0*inv, tg1 = e1*inv;
    float a0 = lgb[4+b*2], a1l = lgb[4+b*2+1];
    m = fmaxf(a0,a1l);
    float f0=__expf(a0-m), f1=__expf(a1l-m); inv = 1.f/(f0+f1);
    float ag0 = f0*inv, ag1 = f1*inv;
    cmb0[b] = ag0*DEPTHF;
    sh[2+b] = tg0*ag1*DEPTHF;
    sh[4+b] = tg1*ag1*DEPTHF;
    sh[6+b] = sh[b]*DEPTHF;
  }
  __syncthreads();
  for (int i = tid; i < BSq; i += 256) {
    int b = i >> 10;
    rs_tg0[i] = sh[2+b]; rs_tg1[i] = sh[4+b]; rs_ffn[i] = sh[6+b];
  }
}
__global__ __launch_bounds__(256)
void gate_fin_kernel(const int* __restrict__ flag, const float* g1b, const float* lgb,
    const void* w2, const void* b2, float* cmb0,
    float* rs_tg0, float* rs_tg1, float* rs_ffn)
{
  __shared__ float sh[8];
  if (*flag) gfin_body<bf16>(sh, g1b, lgb, (const bf16*)w2, (const bf16*)b2, cmb0, rs_tg0, rs_tg1, rs_ffn);
  else       gfin_body<float>(sh, g1b, lgb, (const float*)w2, (const float*)b2, cmb0, rs_tg0, rs_tg1, rs_ffn);
}

// ---------------- MoE router ----------------
template<typename IT>
__device__ void router_body(const IT* __restrict__ x, const IT* __restrict__ wr,
                            const IT* __restrict__ br, const float* __restrict__ cmb0,
                            float* __restrict__ gates_t)
{
  int row = blockIdx.x;
  int tid = threadIdx.x;
  size_t off = (size_t)row*Dq;
  float a0=0,a1=0,a2=0,a3=0;
  for (int dd = tid; dd < Dq; dd += 64) {
    float xv = toF(x[off+dd]);
    a0 += xv*toF(wr[dd*Eq+0]);
    a1 += xv*toF(wr[dd*Eq+1]);
    a2 += xv*toF(wr[dd*Eq+2]);
    a3 += xv*toF(wr[dd*Eq+3]);
  }
#pragma unroll
  for (int o=32;o>=1;o>>=1) {
    a0 += __shfl_xor(a0,o); a1 += __shfl_xor(a1,o);
    a2 += __shfl_xor(a2,o); a3 += __shfl_xor(a3,o);
  }
  if (tid == 0) {
    a0 += toF(br[0]); a1 += toF(br[1]); a2 += toF(br[2]); a3 += toF(br[3]);
    float m = fmaxf(fmaxf(a0,a1),fmaxf(a2,a3));
    float e0=__expf(a0-m), e1=__expf(a1-m), e2=__expf(a2-m), e3=__expf(a3-m);
    float inv = 1.f/(e0+e1+e2+e3);
    float sc = cmb0[row >> 10];
    gates_t[0*BSq+row]=e0*inv*sc; gates_t[1*BSq+row]=e1*inv*sc;
    gates_t[2*BSq+row]=e2*inv*sc; gates_t[3*BSq+row]=e3*inv*sc;
  }
}
__global__ __launch_bounds__(64)
void router_kernel(const int* __restrict__ flag, const void* x, const void* wr,
                   const void* br, const float* cmb0, float* gates_t)
{
  if (*flag) router_body<bf16>((const bf16*)x, (const bf16*)wr, (const bf16*)br, cmb0, gates_t);
  else       router_body<float>((const float*)x, (const float*)wr, (const float*)br, cmb0, gates_t);
}

extern "C" void kernel_launch(void* const* d_in, const int* in_sizes, int n_in,
                              void* d_out, int out_size, void* d_ws, size_t ws_size,
                              hipStream_t stream) {
  const void* x      = d_in[0];
  const void* arg_w1 = d_in[1];  const void* arg_b1 = d_in[2];
  const void* arg_w2 = d_in[3];  const void* arg_b2 = d_in[4];
  const void* moe_wr = d_in[5];  const void* moe_br = d_in[6];
  const void* moe_wq = d_in[7];  const void* moe_bq = d_in[8];
  const void* moe_wk = d_in[9];  const void* moe_bk = d_in[10];
  const void* moe_wv = d_in[11]; const void* moe_bv = d_in[12];
  const void* moe_wo = d_in[13]; const void* moe_bo = d_in[14];
  const void* sp_wq  = d_in[15]; const void* sp_bq  = d_in[16];
  const void* sp_wk  = d_in[17]; const void* sp_bk  = d_in[18];
  const void* sp_wv  = d_in[19]; const void* sp_bv  = d_in[20];
  const void* sp_wo  = d_in[21]; const void* sp_bo  = d_in[22];
  const void* pf_wq  = d_in[23]; const void* pf_bq  = d_in[24];
  const void* pf_wk  = d_in[25]; const void* pf_bk  = d_in[26];
  const void* pf_wv  = d_in[27]; const void* pf_bv  = d_in[28];
  const void* pf_wo  = d_in[29]; const void* pf_bo  = d_in[30];
  const void* pf_wf  = d_in[31];
  const void* taa_wg = d_in[32]; const void* taa_bg = d_in[33];
  const void* ag_w   = d_in[34]; const void* ag_b   = d_in[35];
  const void* ffn_w1 = d_in[36]; const void* ffn_b1 = d_in[37];
  const void* ffn_w2 = d_in[38]; const void* ffn_b2 = d_in[39];
  const void* n1_g   = d_in[40]; const void* n1_b   = d_in[41];
  const void* n2_g   = d_in[42]; const void* n2_b   = d_in[43];
  const void* n3_g   = d_in[44]; const void* n3_b   = d_in[45];

  char* w = (char*)d_ws;
  const size_t MB = 1024*1024;
  // phase 1 (attention):
  bf16* xb  = (bf16*)w;                 // [0,4)
  bf16* Qp  = (bf16*)(w + 4*MB);        // [4,28)  6 Q planes (attn out in place)
  bf16* KV  = (bf16*)(w + 28*MB);       // [28,44) K0,V0,K1,V1
  bf16* Vt  = (bf16*)(w + 44*MB);       // [44,52) Vt0,Vt1
  bf16* Pp  = (bf16*)(w + 28*MB);       // [28,52) 6 O-proj planes (over KV/Vt, dead)
  // phase 2 (FFN):
  bf16* x1    = (bf16*)(w + 4*MB);      // [4,8)
  bf16* ffn_h = (bf16*)(w + 8*MB);      // [8,24)
  float* partF= (float*)(w + 24*MB);    // [24,56) 4 f32 partial planes
  bf16* tmpb  = (bf16*)w;               // [0,4)  (xb dead)
  bf16* x2    = (bf16*)w;               // LN2 writes in place over tmpb (row-safe)
  // bookkeeping:
  char* book = w + 56*MB;
  float* rs_tg0 = (float*)book;
  float* rs_tg1 = rs_tg0 + BSq;
  float* rs_ffn = rs_tg1 + BSq;
  float* cmb0   = rs_ffn + BSq;
  float* avgp   = cmb0 + 16;
  float* gates_t= avgp + Bq*Dq;
  float* zb     = gates_t + Eq*BSq;
  float* g1b    = zb + Bq*Hq*Mq;
  float* lgb    = g1b + 256;
  int*   dflag  = (int*)(lgb + 8);
  bf16*  barena = (bf16*)(dflag + 16);
  bf16*  wft    = barena + 29696;
  bf16*  kvb    = (bf16*)(w + 57*MB);   // [57,58) performer kvT

  detect_kernel<<<1, 256, 0, stream>>>((const unsigned*)x, dflag);
  hipMemsetAsync(avgp, 0, (size_t)(Bq*Dq)*sizeof(float), stream);
  conv_x_kernel<<<BSq*Dq/1024, 256, 0, stream>>>(dflag, x, xb);
  pack_bias_kernel<<<1, 256, 0, stream>>>(dflag, barena,
      moe_bq, moe_bk, moe_bv, moe_bo, sp_bq, sp_bk, sp_bv, sp_bo,
      pf_bq, pf_bk, pf_bv, pf_bo, ffn_b1, ffn_b2);
  pack_wft_kernel<<<64, 256, 0, stream>>>(dflag, pf_wf, wft);
  avg2_kernel<<<Bq*16, 256, 0, stream>>>(dflag, x, avgp);
  gate_dots_kernel<<<66, 256, 0, stream>>>(dflag, avgp, arg_w1, arg_b1,
      taa_wg, taa_bg, ag_w, ag_b, g1b, lgb);
  gate_fin_kernel<<<1, 256, 0, stream>>>(dflag, g1b, lgb, arg_w2, arg_b2,
      cmb0, rs_tg0, rs_tg1, rs_ffn);
  router_kernel<<<BSq, 64, 0, stream>>>(dflag, x, moe_wr, moe_br, cmb0, gates_t);

  dim3 g6(16, 8, 6);
  dim3 gVT(Bq*Hq, Sq/64, 2);
  int nAttnBlk = Bq*Hq*(Sq/16);       // sparse attn (2048)
  int nFlashBlk = Bq*Hq*(Sq/16);      // flash dense v2 (2048)

  // ---- MoE expert attentions, paired ----
  for (int p = 0; p < 2; p++) {
    int e0 = 2*p, e1 = 2*p + 1;
    gemm6_k<<<g6, 256, 0, stream>>>(dflag, xb, 0L,
        moe_wq, moe_wk, moe_wv, moe_wq, moe_wk, moe_wv,
        (long)e0*DD, (long)e0*DD, (long)e0*DD, (long)e1*DD, (long)e1*DD, (long)e1*DD,
        e0*1024, e0*1024+4096, e0*1024+8192, e1*1024, e1*1024+4096, e1*1024+8192,
        nullptr, nullptr, nullptr, nullptr, nullptr, nullptr,
        Qp + (size_t)e0*PLANE, KV, KV + PLANE,
        Qp + (size_t)e1*PLANE, KV + 2*PLANE, KV + 3*PLANE,
        barena, Dq, Dq);
    vtrans_kernel<<<gVT, 256, 0, stream>>>(KV + PLANE, (long)(2*PLANE), Vt, (long)PLANE);
    flash_attn_kernel<<<nFlashBlk, 256, 0, stream>>>(Qp + (size_t)e0*PLANE, KV, Vt, Qp + (size_t)e0*PLANE);
    flash_attn_kernel<<<nFlashBlk, 256, 0, stream>>>(Qp + (size_t)e1*PLANE, KV + 2*PLANE, Vt + PLANE, Qp + (size_t)e1*PLANE);
  }

  // ---- sparse + performer QKV, paired ----
  gemm6_k<<<g6, 256, 0, stream>>>(dflag, xb, 0L,
      sp_wq, sp_wk, sp_wv, pf_wq, pf_wk, pf_wv,
      0L, 0L, 0L, 0L, 0L, 0L,
      16384, 17408, 18432, 20480, 21504, 22528,
      nullptr, nullptr, nullptr, nullptr, nullptr, nullptr,
      Qp + 4*PLANE, KV, KV + PLANE,
      Qp + 5*PLANE, KV + 2*PLANE, KV + 3*PLANE,
      barena, Dq, Dq);
  vtrans_kernel<<<gVT, 256, 0, stream>>>(KV + PLANE, (long)(2*PLANE), Vt, (long)PLANE);
  attn_kernel<1><<<nAttnBlk, 256, 0, stream>>>(Qp + 4*PLANE, KV, Vt, Qp + 4*PLANE);
  {
    dim3 gKV1(Bq*Hq, 8);
    perf_kv_mfma<<<gKV1, 256, 0, stream>>>(KV + 2*PLANE, Vt + PLANE, wft, kvb, zb);
  }
  perf_out_mfma<<<Bq*Hq*16, 256, 0, stream>>>(Qp + 5*PLANE, wft, kvb, zb, Qp + 5*PLANE);

  // ---- all six O-projections in one launch, each to its own plane ----
  gemm6_k<<<g6, 256, 0, stream>>>(dflag, Qp, (long)PLANE,
      moe_wo, moe_wo, moe_wo, moe_wo, sp_wo, pf_wo,
      0L, (long)DD, (long)2*DD, (long)3*DD, 0L, 0L,
      12288, 13312, 14336, 15360, 19456, 23552,
      gates_t, gates_t + BSq, gates_t + 2*BSq, gates_t + 3*BSq, rs_tg0, rs_tg1,
      Pp, Pp + PLANE, Pp + 2*PLANE, Pp + 3*PLANE, Pp + 4*PLANE, Pp + 5*PLANE,
      barena, Dq, Dq);

  // ---- LN1: x + sum of 6 planes -> x1 ----
  ln_kernel<<<BSq, 256, 0, stream>>>(dflag, x, Pp, nullptr, n1_g, n1_b, x1, 3);

  // ---- FFN ----
  gemm1_k<<<dim3(16, 32, 1), 256, 0, stream>>>(dflag, x1, Dq, ffn_w1,
      barena, 24576, nullptr, ffn_h, nullptr, 0L, FFq, Dq, 1, 0);
  gemm1_k<<<dim3(16, 8, 4), 256, 0, stream>>>(dflag, ffn_h, FFq, ffn_w2,
      nullptr, 0, nullptr, nullptr, partF, (long)PLANE, Dq, 1024, 0, 1024);
  combine_ffn2<<<BSq*Dq/1024, 256, 0, stream>>>(partF, barena, rs_ffn, tmpb);

  // ---- LN2, LN3 ----
  ln_kernel<<<BSq, 256, 0, stream>>>(dflag, nullptr, x1, tmpb, n2_g, n2_b, x2, 1);
  ln_kernel<<<BSq, 256, 0, stream>>>(dflag, nullptr, x2, nullptr, n3_g, n3_b, d_out, 2);
}